// Round 9
// baseline (477.377 us; speedup 1.0000x reference)
//
#include <hip/hip_runtime.h>
#include <hip/hip_bf16.h>

#define N_NODES 50000
#define N_EDGES 800000
#define NFEAT 512
#define NHID 128
#define NCLASS 40
#define BN_EPS 1e-5f

typedef __attribute__((ext_vector_type(8))) short short8;
typedef __attribute__((ext_vector_type(4))) float f32x4;

#define GEMM1_BLOCKS ((N_NODES + 127) / 128)   // 391 (BM=128 — proven best)
#define GEMMH_BLOCKS ((N_NODES + 127) / 128)   // 391
#define EDGE_BLOCKS ((N_EDGES + 255) / 256)    // 3125
#define SCAN_BLOCKS ((N_NODES + 255) / 256)    // 196
#define BN_BLOCKS ((N_NODES + 255) / 256)      // 196
#define AGG_BLOCKS ((N_NODES * 64 + 255) / 256) // 12500 (1 wave per node)

__device__ __forceinline__ unsigned short f2b(float f) {
    unsigned int u = __float_as_uint(f);
    u += 0x7fff + ((u >> 16) & 1);   // RTNE
    return (unsigned short)(u >> 16);
}
__device__ __forceinline__ unsigned int pk2(float lo, float hi) {
    unsigned int r;
    asm("v_cvt_pk_bf16_f32 %0, %1, %2" : "=v"(r) : "v"(lo), "v"(hi));
    return r;
}
__device__ __forceinline__ float blo(unsigned int v) {
    return __uint_as_float(v << 16);
}
__device__ __forceinline__ float bhi(unsigned int v) {
    return __uint_as_float(v & 0xffff0000u);
}

// ---------------------------------------------------------------------------
// Weight prep: fp32 W[K][128] -> bf16 W^T[128][K] for W1,W2,W3; zero degcnt,
// stats[768], sync[8].
__global__ void k_prep_w(const float* __restrict__ W1, const float* __restrict__ W2,
                         const float* __restrict__ W3, unsigned short* __restrict__ W1t,
                         unsigned short* __restrict__ W2t, unsigned short* __restrict__ W3t,
                         unsigned long long* __restrict__ degcnt,
                         float* __restrict__ stats, int* __restrict__ syncp) {
    int i = blockIdx.x * blockDim.x + threadIdx.x;
    if (i < N_NODES) degcnt[i] = 0ULL;
    if (i < 768) stats[i] = 0.f;
    else if (i < 776) syncp[i - 768] = 0;
    if (i < 65536) {
        int k = i >> 7, n = i & 127;
        W1t[n * 512 + k] = f2b(W1[i]);
    } else if (i < 81920) {
        int j = i - 65536; int k = j >> 7, n = j & 127;
        W2t[n * 128 + k] = f2b(W2[j]);
    } else if (i < 98304) {
        int j = i - 81920; int k = j >> 7, n = j & 127;
        W3t[n * 128 + k] = f2b(W3[j]);
    }
}

// ---------------------------------------------------------------------------
// FAT kernel. GEMM half is LDS-FREE and BARRIER-FREE: each lane's MFMA
// fragment (A: x[wm+i*16+l15][kt+quad*8..+8], B: W1t[wn+j*16+l15][same k])
// is a contiguous 16-32B global load, wave-level fully cacheline-coalesced.
// The old LDS round-trip cost 32 block barriers per block at ~1.5 waves/SIMD
// (R7: 3.9us/K-iter vs ~1.5us HBM floor). Edge half unchanged.
__global__ __launch_bounds__(256) void k_fat(
    const float* __restrict__ x, const unsigned short* __restrict__ W1t,
    unsigned short* __restrict__ hbuf,
    const unsigned int* __restrict__ words, const float* __restrict__ ew,
    int* __restrict__ row, int* __restrict__ col,
    unsigned long long* __restrict__ degcnt, int* __restrict__ slot) {
    __shared__ int s_any;
    int tid = threadIdx.x;
    if (blockIdx.x < GEMM1_BLOCKS) {
        int m0 = blockIdx.x * 128;
        int wave = tid >> 6, lane = tid & 63;
        int wm = (wave >> 1) * 64, wn = (wave & 1) * 64;
        int l15 = lane & 15, quad = lane >> 4;
        f32x4 acc[4][4] = {};
        const float* ap[4];
        const unsigned short* bp[4];
#pragma unroll
        for (int i = 0; i < 4; i++) {
            int m = m0 + wm + i * 16 + l15;
            ap[i] = x + (size_t)((m < N_NODES) ? m : 0) * 512 + quad * 8;
            bp[i] = W1t + (size_t)(wn + i * 16 + l15) * 512 + quad * 8;
        }
#pragma unroll 2
        for (int kt = 0; kt < 512; kt += 32) {
            short8 a[4], b[4];
#pragma unroll
            for (int i = 0; i < 4; i++) {
                float4 f0 = *(const float4*)(ap[i] + kt);
                float4 f1 = *(const float4*)(ap[i] + kt + 4);
                uint4 pu = make_uint4(pk2(f0.x, f0.y), pk2(f0.z, f0.w),
                                      pk2(f1.x, f1.y), pk2(f1.z, f1.w));
                a[i] = *(const short8*)&pu;
            }
#pragma unroll
            for (int j = 0; j < 4; j++) b[j] = *(const short8*)(bp[j] + kt);
#pragma unroll
            for (int i = 0; i < 4; i++)
#pragma unroll
                for (int j = 0; j < 4; j++)
                    acc[i][j] = __builtin_amdgcn_mfma_f32_16x16x32_bf16(a[i], b[j], acc[i][j], 0, 0, 0);
        }
#pragma unroll
        for (int i = 0; i < 4; i++) {
            int mb = m0 + wm + i * 16 + quad * 4;
#pragma unroll
            for (int r = 0; r < 4; r++) {
                int m = mb + r;
                if (m < N_NODES) {
#pragma unroll
                    for (int j = 0; j < 4; j++)
                        hbuf[(size_t)m * 128 + wn + j * 16 + l15] = f2b(acc[i][j][r]);
                }
            }
        }
    } else {
        // ---- edge convert + degree histogram (per-block inline detect) ----
        if (tid == 0) s_any = 0;
        __syncthreads();
        unsigned int probe = words[2 * tid + 1];
        if (probe != 0) atomicAdd(&s_any, 1);
        __syncthreads();
        int f = (s_any == 0) ? 1 : 0;  // 1 => int64 layout
        int e = (blockIdx.x - GEMM1_BLOCKS) * 256 + tid;
        if (e < N_EDGES) {
            unsigned int r = f ? words[2 * (size_t)e] : words[e];
            unsigned int c = f ? words[2 * ((size_t)e + N_EDGES)] : words[e + N_EDGES];
            row[e] = (int)r;
            col[e] = (int)c;
            unsigned int q = __float2uint_rn(ew[e] * 8388608.0f);  // 2^23 fixed point
            unsigned long long old = atomicAdd(&degcnt[c], (1ULL << 32) | (unsigned long long)q);
            slot[e] = (int)(old >> 32);
        }
    }
}

// ---------------------------------------------------------------------------
// dinv + counts + scan phase-1 block reduction; LAST block (ticket) also
// scans the 196 block sums (one-shot arrivals, no polling).
__global__ __launch_bounds__(256) void k_dinv(const unsigned long long* __restrict__ degcnt,
                                              float* __restrict__ dinv,
                                              int* __restrict__ counts,
                                              int* __restrict__ bsum,
                                              int* __restrict__ ticket,
                                              int* __restrict__ bpre,
                                              int* __restrict__ colptr) {
    int i = blockIdx.x * 256 + threadIdx.x;
    int cnt = 0;
    if (i < N_NODES) {
        unsigned long long v = degcnt[i];
        float deg = 1.0f + (float)(unsigned int)(v & 0xffffffffULL) * (1.0f / 8388608.0f);
        dinv[i] = rsqrtf(deg);
        cnt = (int)(v >> 32);
        counts[i] = cnt;
    }
    __shared__ int sh[256];
    __shared__ int s_last;
    sh[threadIdx.x] = cnt;
    __syncthreads();
    for (int ofs = 128; ofs > 0; ofs >>= 1) {
        if (threadIdx.x < ofs) sh[threadIdx.x] += sh[threadIdx.x + ofs];
        __syncthreads();
    }
    if (threadIdx.x == 0) {
        bsum[blockIdx.x] = sh[0];
        __threadfence();
        int t = atomicAdd(ticket, 1);
        s_last = (t == SCAN_BLOCKS - 1) ? 1 : 0;
    }
    __syncthreads();
    if (s_last) {
        __threadfence();
        int t = threadIdx.x;
        int v = (t < SCAN_BLOCKS) ? ((volatile int*)bsum)[t] : 0;
        sh[t] = v;
        __syncthreads();
        for (int ofs = 1; ofs < 256; ofs <<= 1) {
            int u = (t >= ofs) ? sh[t - ofs] : 0;
            __syncthreads();
            sh[t] += u;
            __syncthreads();
        }
        if (t < SCAN_BLOCKS) bpre[t] = sh[t] - v;  // exclusive
        if (t == SCAN_BLOCKS - 1) colptr[N_NODES] = sh[t];
    }
}

__global__ __launch_bounds__(256) void k_scan3(const int* __restrict__ counts,
                                               const int* __restrict__ bpre,
                                               int* __restrict__ colptr) {
    int t = threadIdx.x;
    int i = blockIdx.x * 256 + t;
    int v = (i < N_NODES) ? counts[i] : 0;
    __shared__ int sh[256];
    sh[t] = v;
    __syncthreads();
    for (int ofs = 1; ofs < 256; ofs <<= 1) {
        int u = (t >= ofs) ? sh[t - ofs] : 0;
        __syncthreads();
        sh[t] += u;
        __syncthreads();
    }
    if (i < N_NODES) colptr[i] = bpre[blockIdx.x] + sh[t] - v;
}

// Atomic-free scatter into interleaved (row, norm) records.
__global__ void k_scatter(const int* __restrict__ row, const int* __restrict__ col,
                          const float* __restrict__ ew, const float* __restrict__ dinv,
                          const int* __restrict__ colptr, const int* __restrict__ slot,
                          int2* __restrict__ ern) {
    int e = blockIdx.x * blockDim.x + threadIdx.x;
    if (e < N_EDGES) {
        int c = col[e], r = row[e];
        int p = colptr[c] + slot[e];
        float nrm = dinv[r] * ew[e] * dinv[c];
        ern[p] = make_int2(r, __float_as_int(nrm));
    }
}

// ---------------------------------------------------------------------------
// CSR aggregation: ONE wave per node, fully-batched 8-edge rounds (clamped
// OOB slots with zero weight — no serial tail). R7-proven.
__global__ __launch_bounds__(256) void k_aggregate(
    const unsigned int* __restrict__ hb, const int* __restrict__ colptr,
    const int2* __restrict__ ern, const float* __restrict__ dinv,
    const float* __restrict__ bias, unsigned int* __restrict__ out, int relu) {
    int node = (blockIdx.x * blockDim.x + threadIdx.x) >> 6;
    int lane = threadIdx.x & 63;
    if (node >= N_NODES) return;
    float di = dinv[node];
    float selfw = di * di;
    unsigned int sv = hb[(size_t)node * 64 + lane];
    float a0 = selfw * blo(sv);
    float a1 = selfw * bhi(sv);
    float c0 = 0.f, c1 = 0.f;
    int start = colptr[node], end = colptr[node + 1];
    for (int e0 = start; e0 < end; e0 += 8) {
        int2 rw[8];
        float wq[8];
#pragma unroll
        for (int q = 0; q < 8; q++) {
            int ee = e0 + q;
            bool ok = ee < end;
            rw[q] = ern[ok ? ee : start];          // clamped, always valid
            wq[q] = ok ? __int_as_float(rw[q].y) : 0.f;
        }
        unsigned int v[8];
#pragma unroll
        for (int q = 0; q < 8; q++) v[q] = hb[(size_t)rw[q].x * 64 + lane];
#pragma unroll
        for (int q = 0; q < 8; q++) {
            if (q & 1) { c0 += wq[q] * blo(v[q]); c1 += wq[q] * bhi(v[q]); }
            else       { a0 += wq[q] * blo(v[q]); a1 += wq[q] * bhi(v[q]); }
        }
    }
    a0 += c0; a1 += c1;
    float2 bv = *(const float2*)&bias[2 * lane];
    a0 += bv.x;
    a1 += bv.y;
    if (relu) { a0 = fmaxf(a0, 0.f); a1 = fmaxf(a1, 0.f); }
    out[(size_t)node * 64 + lane] = pk2(a0, a1);
}

// ---------------------------------------------------------------------------
// BatchNorm stats: 4-row load batching (R7-proven). Buffers zeroed by prep.
__global__ __launch_bounds__(256) void k_bnstats(const unsigned int* __restrict__ x,
                                                 float* __restrict__ sums,
                                                 float* __restrict__ sumsq) {
    int u = threadIdx.x & 63;
    int strip = threadIdx.x >> 6;
    int r0 = blockIdx.x * 256;
    int rend = min(r0 + 256, N_NODES);
    float sl = 0.f, s2l = 0.f, sh_ = 0.f, s2h = 0.f;
    for (int r = r0 + strip; r < rend; r += 16) {
        unsigned int v[4];
#pragma unroll
        for (int k = 0; k < 4; k++) {
            int rr = r + 4 * k;
            v[k] = (rr < rend) ? x[(size_t)rr * 64 + u] : 0u;
        }
#pragma unroll
        for (int k = 0; k < 4; k++) {
            float a = blo(v[k]), b = bhi(v[k]);
            sl += a; s2l += a * a;
            sh_ += b; s2h += b * b;
        }
    }
    __shared__ float buf[4][64][4];
    buf[strip][u][0] = sl; buf[strip][u][1] = s2l;
    buf[strip][u][2] = sh_; buf[strip][u][3] = s2h;
    __syncthreads();
    if (strip == 0) {
#pragma unroll
        for (int s = 1; s < 4; s++) {
            sl += buf[s][u][0]; s2l += buf[s][u][1];
            sh_ += buf[s][u][2]; s2h += buf[s][u][3];
        }
        atomicAdd(&sums[2 * u], sl);
        atomicAdd(&sums[2 * u + 1], sh_);
        atomicAdd(&sumsq[2 * u], s2l);
        atomicAdd(&sumsq[2 * u + 1], s2h);
    }
}

// ---------------------------------------------------------------------------
// Layer-2/3 GEMM, LDS-free load path (same fragment-direct trick as k_fat).
// BN scale/shift computed once into LDS (one barrier), applied in registers
// during the A-fragment load. K=128 -> 4 fully-unrolled iterations.
__global__ __launch_bounds__(256) void k_gemm_h(
    const unsigned int* __restrict__ Ab, const unsigned short* __restrict__ Wt,
    const float* __restrict__ sums, const float* __restrict__ sumsq,
    const float* __restrict__ g, const float* __restrict__ be,
    unsigned short* __restrict__ Out) {
    __shared__ float s_sc[128], s_sh[128];
    int tid = threadIdx.x;
    int m0 = blockIdx.x * 128;
    if (tid < 128) {
        const float invn = 1.0f / (float)N_NODES;
        float mu = sums[tid] * invn;
        float var = sumsq[tid] * invn - mu * mu;
        float iv = rsqrtf(var + BN_EPS);
        float sc = g[tid] * iv;
        s_sc[tid] = sc;
        s_sh[tid] = be[tid] - mu * sc;
    }
    __syncthreads();
    int wave = tid >> 6, lane = tid & 63;
    int wm = (wave >> 1) * 64, wn = (wave & 1) * 64;
    int l15 = lane & 15, quad = lane >> 4;
    f32x4 acc[4][4] = {};
    const unsigned int* ap[4];
    const unsigned short* bp[4];
#pragma unroll
    for (int i = 0; i < 4; i++) {
        int m = m0 + wm + i * 16 + l15;
        ap[i] = Ab + (size_t)((m < N_NODES) ? m : 0) * 64 + quad * 4;
        bp[i] = Wt + (size_t)(wn + i * 16 + l15) * 128 + quad * 8;
    }
#pragma unroll
    for (int kt = 0; kt < 128; kt += 32) {
        float sc[8], sh[8];
        *(float4*)&sc[0] = *(const float4*)&s_sc[kt + quad * 8];
        *(float4*)&sc[4] = *(const float4*)&s_sc[kt + quad * 8 + 4];
        *(float4*)&sh[0] = *(const float4*)&s_sh[kt + quad * 8];
        *(float4*)&sh[4] = *(const float4*)&s_sh[kt + quad * 8 + 4];
        short8 a[4], b[4];
#pragma unroll
        for (int i = 0; i < 4; i++) {
            uint4 raw = *(const uint4*)(ap[i] + (kt >> 1));
            uint4 pu;
            pu.x = pk2(blo(raw.x) * sc[0] + sh[0], bhi(raw.x) * sc[1] + sh[1]);
            pu.y = pk2(blo(raw.y) * sc[2] + sh[2], bhi(raw.y) * sc[3] + sh[3]);
            pu.z = pk2(blo(raw.z) * sc[4] + sh[4], bhi(raw.z) * sc[5] + sh[5]);
            pu.w = pk2(blo(raw.w) * sc[6] + sh[6], bhi(raw.w) * sc[7] + sh[7]);
            a[i] = *(const short8*)&pu;
        }
#pragma unroll
        for (int j = 0; j < 4; j++) b[j] = *(const short8*)(bp[j] + kt);
#pragma unroll
        for (int i = 0; i < 4; i++)
#pragma unroll
            for (int j = 0; j < 4; j++)
                acc[i][j] = __builtin_amdgcn_mfma_f32_16x16x32_bf16(a[i], b[j], acc[i][j], 0, 0, 0);
    }
#pragma unroll
    for (int i = 0; i < 4; i++) {
        int mb = m0 + wm + i * 16 + quad * 4;
#pragma unroll
        for (int r = 0; r < 4; r++) {
            int m = mb + r;
            if (m < N_NODES) {
#pragma unroll
                for (int j = 0; j < 4; j++)
                    Out[(size_t)m * 128 + wn + j * 16 + l15] = f2b(acc[i][j][r]);
            }
        }
    }
}

// ---------------------------------------------------------------------------
// Head: BN3 scale/shift from raw sums (inline), x3 fp32 write, logits+softmax.
__global__ __launch_bounds__(256) void k_logits(const unsigned int* __restrict__ abuf,
                                                const float* __restrict__ sums,
                                                const float* __restrict__ sumsq,
                                                const float* __restrict__ g,
                                                const float* __restrict__ be,
                                                const float* __restrict__ linW,
                                                const float* __restrict__ linb,
                                                float* __restrict__ logits,
                                                float* __restrict__ probs,
                                                float* __restrict__ x3out) {
    __shared__ float Xs[64][130];
    __shared__ float Ws[128 * 40];
    __shared__ float s_sc[128], s_sh[128];
    int tid = threadIdx.x;
    int m0 = blockIdx.x * 64;
    if (tid < 128) {
        const float invn = 1.0f / (float)N_NODES;
        float mu = sums[tid] * invn;
        float var = sumsq[tid] * invn - mu * mu;
        float iv = rsqrtf(var + BN_EPS);
        float sc = g[tid] * iv;
        s_sc[tid] = sc;
        s_sh[tid] = be[tid] - mu * sc;
    }
    for (int q = tid; q < 1280; q += 256)
        *(float4*)&Ws[q * 4] = *(const float4*)&linW[q * 4];
    __syncthreads();
    for (int q = tid; q < 4096; q += 256) {
        int r = q >> 6, u = q & 63;
        int m = m0 + r;
        float f0 = 0.f, f1 = 0.f;
        if (m < N_NODES) {
            unsigned int v = abuf[(size_t)m * 64 + u];
            f0 = blo(v) * s_sc[2 * u] + s_sh[2 * u];
            f1 = bhi(v) * s_sc[2 * u + 1] + s_sh[2 * u + 1];
            *(float2*)&x3out[(size_t)m * 128 + 2 * u] = make_float2(f0, f1);
        }
        *(float2*)&Xs[r][2 * u] = make_float2(f0, f1);
    }
    __syncthreads();
    int r = tid >> 2;
    int cg = tid & 3;
    int cbase = cg * 10;
    float acc[10] = {};
    for (int k = 0; k < 128; k++) {
        float a = Xs[r][k];
#pragma unroll
        for (int j = 0; j < 10; j++) acc[j] += a * Ws[k * 40 + cbase + j];
    }
#pragma unroll
    for (int j = 0; j < 10; j++) acc[j] += linb[cbase + j];
    float m = acc[0];
#pragma unroll
    for (int j = 1; j < 10; j++) m = fmaxf(m, acc[j]);
    m = fmaxf(m, __shfl_xor(m, 1));
    m = fmaxf(m, __shfl_xor(m, 2));
    float ex[10];
    float s = 0.f;
#pragma unroll
    for (int j = 0; j < 10; j++) { ex[j] = expf(acc[j] - m); s += ex[j]; }
    s += __shfl_xor(s, 1);
    s += __shfl_xor(s, 2);
    float inv = 1.0f / s;
    int mrow = m0 + r;
    if (mrow < N_NODES) {
#pragma unroll
        for (int j = 0; j < 10; j += 2) {
            *(float2*)&logits[(size_t)mrow * 40 + cbase + j] = make_float2(acc[j], acc[j + 1]);
            *(float2*)&probs[(size_t)mrow * 40 + cbase + j] = make_float2(ex[j] * inv, ex[j + 1] * inv);
        }
    }
}

// ---------------------------------------------------------------------------
extern "C" void kernel_launch(void* const* d_in, const int* in_sizes, int n_in,
                              void* d_out, int out_size, void* d_ws, size_t ws_size,
                              hipStream_t stream) {
    const float* x = (const float*)d_in[0];
    const unsigned int* eidx = (const unsigned int*)d_in[1];
    const float* ew = (const float*)d_in[2];
    const float* W1 = (const float*)d_in[3];
    const float* b1 = (const float*)d_in[4];
    const float* W2 = (const float*)d_in[5];
    const float* b2 = (const float*)d_in[6];
    const float* W3 = (const float*)d_in[7];
    const float* b3 = (const float*)d_in[8];
    const float* g1 = (const float*)d_in[9];
    const float* be1 = (const float*)d_in[10];
    const float* g2 = (const float*)d_in[11];
    const float* be2 = (const float*)d_in[12];
    const float* g3 = (const float*)d_in[13];
    const float* be3 = (const float*)d_in[14];
    const float* linW = (const float*)d_in[15];
    const float* linb = (const float*)d_in[16];

    float* out = (float*)d_out;
    float* logits = out;
    float* probs = out + (size_t)N_NODES * NCLASS;
    float* x3out = out + 2 * (size_t)N_NODES * NCLASS;

    char* ws = (char*)d_ws;
    size_t off = 0;
    auto take = [&](size_t bytes) -> char* {
        char* p = ws + off;
        off += (bytes + 255) & ~(size_t)255;
        return p;
    };
    int* row32 = (int*)take((size_t)N_EDGES * 4);
    int* col32 = (int*)take((size_t)N_EDGES * 4);
    int* slot = (int*)take((size_t)N_EDGES * 4);
    int* colptr = (int*)take((size_t)(N_NODES + 1) * 4);
    int* counts = (int*)take((size_t)N_NODES * 4);
    unsigned long long* degcnt = (unsigned long long*)take((size_t)N_NODES * 8);
    int2* ern = (int2*)take((size_t)N_EDGES * 8);
    float* dinv = (float*)take((size_t)N_NODES * 4);
    unsigned short* hbuf = (unsigned short*)take((size_t)N_NODES * NHID * 2);
    unsigned short* abuf = (unsigned short*)take((size_t)N_NODES * NHID * 2);
    unsigned short* W1t = (unsigned short*)take((size_t)512 * 128 * 2);
    unsigned short* W2t = (unsigned short*)take((size_t)128 * 128 * 2);
    unsigned short* W3t = (unsigned short*)take((size_t)128 * 128 * 2);
    float* stats = (float*)take(768 * 4);   // [sums1|sumsq1|sums2|sumsq2|sums3|sumsq3]
    int* syncp = (int*)take(8 * 4);         // [0]=dinv ticket
    int* bsum = (int*)take((size_t)SCAN_BLOCKS * 4);
    int* bpre = (int*)take((size_t)SCAN_BLOCKS * 4);
    (void)ws_size; (void)n_in; (void)in_sizes; (void)out_size;

    float* sums1 = stats, *sumsq1 = stats + 128;
    float* sums2 = stats + 256, *sumsq2 = stats + 384;
    float* sums3 = stats + 512, *sumsq3 = stats + 640;

    const int TPB = 256;

    // preprocessing + layer-1 GEMM overlapped with edge histogram (fat)
    k_prep_w<<<(98304 + TPB - 1) / TPB, TPB, 0, stream>>>(W1, W2, W3, W1t, W2t, W3t, degcnt, stats, syncp);
    k_fat<<<GEMM1_BLOCKS + EDGE_BLOCKS, TPB, 0, stream>>>(
        x, W1t, hbuf, eidx, ew, row32, col32, degcnt, slot);
    k_dinv<<<SCAN_BLOCKS, TPB, 0, stream>>>(degcnt, dinv, counts, bsum, &syncp[0], bpre, colptr);
    k_scan3<<<SCAN_BLOCKS, TPB, 0, stream>>>(counts, bpre, colptr);
    k_scatter<<<EDGE_BLOCKS, TPB, 0, stream>>>(row32, col32, ew, dinv, colptr, slot, ern);

    // layer 1
    k_aggregate<<<AGG_BLOCKS, TPB, 0, stream>>>((const unsigned int*)hbuf, colptr, ern, dinv, b1, (unsigned int*)abuf, 1);
    k_bnstats<<<BN_BLOCKS, TPB, 0, stream>>>((const unsigned int*)abuf, sums1, sumsq1);

    // layer 2 (BN1 applied inline in GEMM prologue from raw sums)
    k_gemm_h<<<GEMMH_BLOCKS, TPB, 0, stream>>>((const unsigned int*)abuf, W2t, sums1, sumsq1, g1, be1, hbuf);
    k_aggregate<<<AGG_BLOCKS, TPB, 0, stream>>>((const unsigned int*)hbuf, colptr, ern, dinv, b2, (unsigned int*)abuf, 1);
    k_bnstats<<<BN_BLOCKS, TPB, 0, stream>>>((const unsigned int*)abuf, sums2, sumsq2);

    // layer 3
    k_gemm_h<<<GEMMH_BLOCKS, TPB, 0, stream>>>((const unsigned int*)abuf, W3t, sums2, sumsq2, g2, be2, hbuf);
    k_aggregate<<<AGG_BLOCKS, TPB, 0, stream>>>((const unsigned int*)hbuf, colptr, ern, dinv, b3, (unsigned int*)abuf, 0);
    k_bnstats<<<BN_BLOCKS, TPB, 0, stream>>>((const unsigned int*)abuf, sums3, sumsq3);

    // head: BN3 apply (inline) + x3 write + logits + softmax
    k_logits<<<(N_NODES + 63) / 64, TPB, 0, stream>>>((const unsigned int*)abuf, sums3, sumsq3, g3, be3, linW, linb, logits, probs, x3out);
}

// Round 13
// 461.075 us; speedup vs baseline: 1.0354x; 1.0354x over previous
//
#include <hip/hip_runtime.h>
#include <hip/hip_bf16.h>

#define N_NODES 50000
#define N_EDGES 800000
#define NFEAT 512
#define NHID 128
#define NCLASS 40
#define BN_EPS 1e-5f

typedef __attribute__((ext_vector_type(8))) short short8;
typedef __attribute__((ext_vector_type(4))) float f32x4;

#define GEMM1_BLOCKS ((N_NODES + 127) / 128)   // 391 (BM=128)
#define GEMMH_BLOCKS ((N_NODES + 127) / 128)   // 391
#define EDGE_BLOCKS_F ((N_EDGES + 511) / 512)  // 1563 (512-thread fat blocks)
#define EDGE_BLOCKS ((N_EDGES + 255) / 256)    // 3125
#define SCAN_BLOCKS ((N_NODES + 255) / 256)    // 196
#define BN_BLOCKS ((N_NODES + 255) / 256)      // 196
#define AGG_BLOCKS ((N_NODES * 64 + 255) / 256) // 12500 (1 wave per node)

__device__ __forceinline__ unsigned short f2b(float f) {
    unsigned int u = __float_as_uint(f);
    u += 0x7fff + ((u >> 16) & 1);   // RTNE
    return (unsigned short)(u >> 16);
}
__device__ __forceinline__ unsigned int pk2(float lo, float hi) {
    unsigned int r;
    asm("v_cvt_pk_bf16_f32 %0, %1, %2" : "=v"(r) : "v"(lo), "v"(hi));
    return r;
}
__device__ __forceinline__ float blo(unsigned int v) {
    return __uint_as_float(v << 16);
}
__device__ __forceinline__ float bhi(unsigned int v) {
    return __uint_as_float(v & 0xffff0000u);
}

// ---------------------------------------------------------------------------
// Weight prep: fp32 W[K][128] -> bf16 W^T[128][K] for W1,W2,W3; zero degcnt,
// stats[768], sync[8].
__global__ void k_prep_w(const float* __restrict__ W1, const float* __restrict__ W2,
                         const float* __restrict__ W3, unsigned short* __restrict__ W1t,
                         unsigned short* __restrict__ W2t, unsigned short* __restrict__ W3t,
                         unsigned long long* __restrict__ degcnt,
                         float* __restrict__ stats, int* __restrict__ syncp) {
    int i = blockIdx.x * blockDim.x + threadIdx.x;
    if (i < N_NODES) degcnt[i] = 0ULL;
    if (i < 768) stats[i] = 0.f;
    else if (i < 776) syncp[i - 768] = 0;
    if (i < 65536) {
        int k = i >> 7, n = i & 127;
        W1t[n * 512 + k] = f2b(W1[i]);
    } else if (i < 81920) {
        int j = i - 65536; int k = j >> 7, n = j & 127;
        W2t[n * 128 + k] = f2b(W2[j]);
    } else if (i < 98304) {
        int j = i - 81920; int k = j >> 7, n = j & 127;
        W3t[n * 128 + k] = f2b(W3[j]);
    }
}

// ---------------------------------------------------------------------------
// FAT kernel, 512 threads. GEMM half: R7's proven LDS structure (BM=128
// BN=128 BK=32, K=512, reg prefetch across barrier) but with 8 WAVES per
// block (wave-tile 32x64). Same tile, same LDS bytes, same barrier count —
// waves/SIMD 1.53 -> 3.05 so another wave can issue during each block's
// staging drain (R1/R7/R3/R9 evidence: k_fat is grid-wave-starved, not
// bound by barriers alone or memory). Edge half unchanged logic.
__global__ __launch_bounds__(512) void k_fat(
    const float* __restrict__ x, const unsigned short* __restrict__ W1t,
    unsigned short* __restrict__ hbuf,
    const unsigned int* __restrict__ words, const float* __restrict__ ew,
    int* __restrict__ row, int* __restrict__ col,
    unsigned long long* __restrict__ degcnt, int* __restrict__ slot) {
    __shared__ unsigned short As[128][40];
    __shared__ unsigned short Bs[128][40];
    __shared__ int s_any;
    int tid = threadIdx.x;
    if (blockIdx.x < GEMM1_BLOCKS) {
        // ---- layer-1 GEMM: BM=128 BN=128 BK=32, K=512, 8 waves ----
        int m0 = blockIdx.x * 128;
        int srow = tid >> 2;            // 0..127
        int ska = (tid & 3) << 3;       // 0,8,16,24
        int wave = tid >> 6, lane = tid & 63;
        int wm = (wave & 3) << 5;       // 0,32,64,96
        int wn = (wave >> 2) << 6;      // 0,64
        int l15 = lane & 15, quad = lane >> 4;
        f32x4 acc[2][4] = {};
        bool arow_ok = (m0 + srow) < N_NODES;
        const float* arow_p = x + (size_t)(m0 + srow) * 512 + ska;
        const unsigned short* wrow_p = W1t + (size_t)srow * 512 + ska;
        float4 ta0 = make_float4(0.f, 0.f, 0.f, 0.f), ta1 = ta0;
        uint4 tb;
        if (arow_ok) {
            ta0 = *(const float4*)(arow_p);
            ta1 = *(const float4*)(arow_p + 4);
        }
        tb = *(const uint4*)(wrow_p);
        for (int kt = 0; kt < 512; kt += 32) {
            unsigned int p0 = pk2(ta0.x, ta0.y), p1 = pk2(ta0.z, ta0.w);
            unsigned int p2 = pk2(ta1.x, ta1.y), p3 = pk2(ta1.z, ta1.w);
            *(uint4*)&As[srow][ska] = make_uint4(p0, p1, p2, p3);
            *(uint4*)&Bs[srow][ska] = tb;
            __syncthreads();
            if (kt + 32 < 512) {   // prefetch next K-tile under ds_read+MFMA
                if (arow_ok) {
                    ta0 = *(const float4*)(arow_p + kt + 32);
                    ta1 = *(const float4*)(arow_p + kt + 36);
                }
                tb = *(const uint4*)(wrow_p + kt + 32);
            }
            short8 a[2], b[4];
#pragma unroll
            for (int i = 0; i < 2; i++) a[i] = *(const short8*)&As[wm + i * 16 + l15][quad * 8];
#pragma unroll
            for (int j = 0; j < 4; j++) b[j] = *(const short8*)&Bs[wn + j * 16 + l15][quad * 8];
#pragma unroll
            for (int i = 0; i < 2; i++)
#pragma unroll
                for (int j = 0; j < 4; j++)
                    acc[i][j] = __builtin_amdgcn_mfma_f32_16x16x32_bf16(a[i], b[j], acc[i][j], 0, 0, 0);
            __syncthreads();
        }
#pragma unroll
        for (int i = 0; i < 2; i++) {
            int mb = m0 + wm + i * 16 + quad * 4;
#pragma unroll
            for (int r = 0; r < 4; r++) {
                int m = mb + r;
                if (m < N_NODES) {
#pragma unroll
                    for (int j = 0; j < 4; j++)
                        hbuf[(size_t)m * 128 + wn + j * 16 + l15] = f2b(acc[i][j][r]);
                }
            }
        }
    } else {
        // ---- edge convert + degree histogram (per-block inline detect) ----
        if (tid == 0) s_any = 0;
        __syncthreads();
        unsigned int probe = words[2 * tid + 1];
        if (probe != 0) atomicAdd(&s_any, 1);
        __syncthreads();
        int f = (s_any == 0) ? 1 : 0;  // 1 => int64 layout
        int e = (blockIdx.x - GEMM1_BLOCKS) * 512 + tid;
        if (e < N_EDGES) {
            unsigned int r = f ? words[2 * (size_t)e] : words[e];
            unsigned int c = f ? words[2 * ((size_t)e + N_EDGES)] : words[e + N_EDGES];
            row[e] = (int)r;
            col[e] = (int)c;
            unsigned int q = __float2uint_rn(ew[e] * 8388608.0f);  // 2^23 fixed point
            unsigned long long old = atomicAdd(&degcnt[c], (1ULL << 32) | (unsigned long long)q);
            slot[e] = (int)(old >> 32);
        }
    }
}

// ---------------------------------------------------------------------------
// dinv + counts + scan phase-1 block reduction; LAST block (ticket) also
// scans the 196 block sums (one-shot arrivals, no polling).
__global__ __launch_bounds__(256) void k_dinv(const unsigned long long* __restrict__ degcnt,
                                              float* __restrict__ dinv,
                                              int* __restrict__ counts,
                                              int* __restrict__ bsum,
                                              int* __restrict__ ticket,
                                              int* __restrict__ bpre,
                                              int* __restrict__ colptr) {
    int i = blockIdx.x * 256 + threadIdx.x;
    int cnt = 0;
    if (i < N_NODES) {
        unsigned long long v = degcnt[i];
        float deg = 1.0f + (float)(unsigned int)(v & 0xffffffffULL) * (1.0f / 8388608.0f);
        dinv[i] = rsqrtf(deg);
        cnt = (int)(v >> 32);
        counts[i] = cnt;
    }
    __shared__ int sh[256];
    __shared__ int s_last;
    sh[threadIdx.x] = cnt;
    __syncthreads();
    for (int ofs = 128; ofs > 0; ofs >>= 1) {
        if (threadIdx.x < ofs) sh[threadIdx.x] += sh[threadIdx.x + ofs];
        __syncthreads();
    }
    if (threadIdx.x == 0) {
        bsum[blockIdx.x] = sh[0];
        __threadfence();
        int t = atomicAdd(ticket, 1);
        s_last = (t == SCAN_BLOCKS - 1) ? 1 : 0;
    }
    __syncthreads();
    if (s_last) {
        __threadfence();
        int t = threadIdx.x;
        int v = (t < SCAN_BLOCKS) ? ((volatile int*)bsum)[t] : 0;
        sh[t] = v;
        __syncthreads();
        for (int ofs = 1; ofs < 256; ofs <<= 1) {
            int u = (t >= ofs) ? sh[t - ofs] : 0;
            __syncthreads();
            sh[t] += u;
            __syncthreads();
        }
        if (t < SCAN_BLOCKS) bpre[t] = sh[t] - v;  // exclusive
        if (t == SCAN_BLOCKS - 1) colptr[N_NODES] = sh[t];
    }
}

__global__ __launch_bounds__(256) void k_scan3(const int* __restrict__ counts,
                                               const int* __restrict__ bpre,
                                               int* __restrict__ colptr) {
    int t = threadIdx.x;
    int i = blockIdx.x * 256 + t;
    int v = (i < N_NODES) ? counts[i] : 0;
    __shared__ int sh[256];
    sh[t] = v;
    __syncthreads();
    for (int ofs = 1; ofs < 256; ofs <<= 1) {
        int u = (t >= ofs) ? sh[t - ofs] : 0;
        __syncthreads();
        sh[t] += u;
        __syncthreads();
    }
    if (i < N_NODES) colptr[i] = bpre[blockIdx.x] + sh[t] - v;
}

// Atomic-free scatter into interleaved (row, norm) records.
__global__ void k_scatter(const int* __restrict__ row, const int* __restrict__ col,
                          const float* __restrict__ ew, const float* __restrict__ dinv,
                          const int* __restrict__ colptr, const int* __restrict__ slot,
                          int2* __restrict__ ern) {
    int e = blockIdx.x * blockDim.x + threadIdx.x;
    if (e < N_EDGES) {
        int c = col[e], r = row[e];
        int p = colptr[c] + slot[e];
        float nrm = dinv[r] * ew[e] * dinv[c];
        ern[p] = make_int2(r, __float_as_int(nrm));
    }
}

// ---------------------------------------------------------------------------
// CSR aggregation: ONE wave per node, fully-batched 8-edge rounds (clamped
// OOB slots with zero weight — no serial tail). R7-proven.
__global__ __launch_bounds__(256) void k_aggregate(
    const unsigned int* __restrict__ hb, const int* __restrict__ colptr,
    const int2* __restrict__ ern, const float* __restrict__ dinv,
    const float* __restrict__ bias, unsigned int* __restrict__ out, int relu) {
    int node = (blockIdx.x * blockDim.x + threadIdx.x) >> 6;
    int lane = threadIdx.x & 63;
    if (node >= N_NODES) return;
    float di = dinv[node];
    float selfw = di * di;
    unsigned int sv = hb[(size_t)node * 64 + lane];
    float a0 = selfw * blo(sv);
    float a1 = selfw * bhi(sv);
    float c0 = 0.f, c1 = 0.f;
    int start = colptr[node], end = colptr[node + 1];
    for (int e0 = start; e0 < end; e0 += 8) {
        int2 rw[8];
        float wq[8];
#pragma unroll
        for (int q = 0; q < 8; q++) {
            int ee = e0 + q;
            bool ok = ee < end;
            rw[q] = ern[ok ? ee : start];          // clamped, always valid
            wq[q] = ok ? __int_as_float(rw[q].y) : 0.f;
        }
        unsigned int v[8];
#pragma unroll
        for (int q = 0; q < 8; q++) v[q] = hb[(size_t)rw[q].x * 64 + lane];
#pragma unroll
        for (int q = 0; q < 8; q++) {
            if (q & 1) { c0 += wq[q] * blo(v[q]); c1 += wq[q] * bhi(v[q]); }
            else       { a0 += wq[q] * blo(v[q]); a1 += wq[q] * bhi(v[q]); }
        }
    }
    a0 += c0; a1 += c1;
    float2 bv = *(const float2*)&bias[2 * lane];
    a0 += bv.x;
    a1 += bv.y;
    if (relu) { a0 = fmaxf(a0, 0.f); a1 = fmaxf(a1, 0.f); }
    out[(size_t)node * 64 + lane] = pk2(a0, a1);
}

// ---------------------------------------------------------------------------
// BatchNorm stats: 4-row load batching (R7-proven). Buffers zeroed by prep.
__global__ __launch_bounds__(256) void k_bnstats(const unsigned int* __restrict__ x,
                                                 float* __restrict__ sums,
                                                 float* __restrict__ sumsq) {
    int u = threadIdx.x & 63;
    int strip = threadIdx.x >> 6;
    int r0 = blockIdx.x * 256;
    int rend = min(r0 + 256, N_NODES);
    float sl = 0.f, s2l = 0.f, sh_ = 0.f, s2h = 0.f;
    for (int r = r0 + strip; r < rend; r += 16) {
        unsigned int v[4];
#pragma unroll
        for (int k = 0; k < 4; k++) {
            int rr = r + 4 * k;
            v[k] = (rr < rend) ? x[(size_t)rr * 64 + u] : 0u;
        }
#pragma unroll
        for (int k = 0; k < 4; k++) {
            float a = blo(v[k]), b = bhi(v[k]);
            sl += a; s2l += a * a;
            sh_ += b; s2h += b * b;
        }
    }
    __shared__ float buf[4][64][4];
    buf[strip][u][0] = sl; buf[strip][u][1] = s2l;
    buf[strip][u][2] = sh_; buf[strip][u][3] = s2h;
    __syncthreads();
    if (strip == 0) {
#pragma unroll
        for (int s = 1; s < 4; s++) {
            sl += buf[s][u][0]; s2l += buf[s][u][1];
            sh_ += buf[s][u][2]; s2h += buf[s][u][3];
        }
        atomicAdd(&sums[2 * u], sl);
        atomicAdd(&sums[2 * u + 1], sh_);
        atomicAdd(&sumsq[2 * u], s2l);
        atomicAdd(&sumsq[2 * u + 1], s2h);
    }
}

// ---------------------------------------------------------------------------
// Layer-2/3 GEMM (R7-proven LDS version): A bf16-packed [M,64 uints], BN
// scale/shift computed inline in the prologue. K=128, reg prefetch.
__global__ __launch_bounds__(256) void k_gemm_h(
    const unsigned int* __restrict__ Ab, const unsigned short* __restrict__ Wt,
    const float* __restrict__ sums, const float* __restrict__ sumsq,
    const float* __restrict__ g, const float* __restrict__ be,
    unsigned short* __restrict__ Out) {
    __shared__ unsigned short As[128][40];
    __shared__ unsigned short Bs[128][40];
    __shared__ float s_sc[128], s_sh[128];
    int tid = threadIdx.x;
    int m0 = blockIdx.x * 128;
    if (tid < 128) {
        const float invn = 1.0f / (float)N_NODES;
        float mu = sums[tid] * invn;
        float var = sumsq[tid] * invn - mu * mu;
        float iv = rsqrtf(var + BN_EPS);
        float sc = g[tid] * iv;
        s_sc[tid] = sc;
        s_sh[tid] = be[tid] - mu * sc;
    }
    __syncthreads();
    int srow = tid >> 1;
    int skh = (tid & 1) << 4;
    int wave = tid >> 6, lane = tid & 63;
    int wm = (wave >> 1) * 64, wn = (wave & 1) * 64;
    int l15 = lane & 15, quad = lane >> 4;
    f32x4 acc[4][4] = {};
    bool arow_ok = (m0 + srow) < N_NODES;
    const unsigned int* arow_b = Ab + (size_t)(m0 + srow) * 64 + (skh >> 1);
    const unsigned short* wrow_p = Wt + (size_t)srow * 128 + skh;
    uint4 r0 = make_uint4(0, 0, 0, 0), r1 = make_uint4(0, 0, 0, 0);
    uint4 tb0, tb1;
    if (arow_ok) {
        r0 = *(const uint4*)(arow_b);
        r1 = *(const uint4*)(arow_b + 4);
    }
    tb0 = *(const uint4*)(wrow_p);
    tb1 = *(const uint4*)(wrow_p + 8);
    for (int kt = 0; kt < 128; kt += 32) {
        unsigned int raw[8] = {r0.x, r0.y, r0.z, r0.w, r1.x, r1.y, r1.z, r1.w};
        unsigned int p[8];
#pragma unroll
        for (int q = 0; q < 8; q++) {
            int ch = kt + skh + 2 * q;
            float f0 = blo(raw[q]) * s_sc[ch] + s_sh[ch];
            float f1 = bhi(raw[q]) * s_sc[ch + 1] + s_sh[ch + 1];
            p[q] = pk2(f0, f1);
        }
        *(uint4*)&As[srow][skh] = make_uint4(p[0], p[1], p[2], p[3]);
        *(uint4*)&As[srow][skh + 8] = make_uint4(p[4], p[5], p[6], p[7]);
        *(uint4*)&Bs[srow][skh] = tb0;
        *(uint4*)&Bs[srow][skh + 8] = tb1;
        __syncthreads();
        if (kt + 32 < 128) {   // prefetch next K-tile under ds_read+MFMA
            if (arow_ok) {
                r0 = *(const uint4*)(arow_b + ((kt + 32) >> 1));
                r1 = *(const uint4*)(arow_b + ((kt + 32) >> 1) + 4);
            }
            tb0 = *(const uint4*)(wrow_p + kt + 32);
            tb1 = *(const uint4*)(wrow_p + kt + 40);
        }
        short8 a[4], b[4];
#pragma unroll
        for (int i = 0; i < 4; i++) a[i] = *(const short8*)&As[wm + i * 16 + l15][quad * 8];
#pragma unroll
        for (int j = 0; j < 4; j++) b[j] = *(const short8*)&Bs[wn + j * 16 + l15][quad * 8];
#pragma unroll
        for (int i = 0; i < 4; i++)
#pragma unroll
            for (int j = 0; j < 4; j++)
                acc[i][j] = __builtin_amdgcn_mfma_f32_16x16x32_bf16(a[i], b[j], acc[i][j], 0, 0, 0);
        __syncthreads();
    }
#pragma unroll
    for (int i = 0; i < 4; i++) {
        int mb = m0 + wm + i * 16 + quad * 4;
#pragma unroll
        for (int r = 0; r < 4; r++) {
            int m = mb + r;
            if (m < N_NODES) {
#pragma unroll
                for (int j = 0; j < 4; j++)
                    Out[(size_t)m * 128 + wn + j * 16 + l15] = f2b(acc[i][j][r]);
            }
        }
    }
}

// ---------------------------------------------------------------------------
// Head: BN3 scale/shift from raw sums (inline), x3 fp32 write, logits+softmax.
__global__ __launch_bounds__(256) void k_logits(const unsigned int* __restrict__ abuf,
                                                const float* __restrict__ sums,
                                                const float* __restrict__ sumsq,
                                                const float* __restrict__ g,
                                                const float* __restrict__ be,
                                                const float* __restrict__ linW,
                                                const float* __restrict__ linb,
                                                float* __restrict__ logits,
                                                float* __restrict__ probs,
                                                float* __restrict__ x3out) {
    __shared__ float Xs[64][130];
    __shared__ float Ws[128 * 40];
    __shared__ float s_sc[128], s_sh[128];
    int tid = threadIdx.x;
    int m0 = blockIdx.x * 64;
    if (tid < 128) {
        const float invn = 1.0f / (float)N_NODES;
        float mu = sums[tid] * invn;
        float var = sumsq[tid] * invn - mu * mu;
        float iv = rsqrtf(var + BN_EPS);
        float sc = g[tid] * iv;
        s_sc[tid] = sc;
        s_sh[tid] = be[tid] - mu * sc;
    }
    for (int q = tid; q < 1280; q += 256)
        *(float4*)&Ws[q * 4] = *(const float4*)&linW[q * 4];
    __syncthreads();
    for (int q = tid; q < 4096; q += 256) {
        int r = q >> 6, u = q & 63;
        int m = m0 + r;
        float f0 = 0.f, f1 = 0.f;
        if (m < N_NODES) {
            unsigned int v = abuf[(size_t)m * 64 + u];
            f0 = blo(v) * s_sc[2 * u] + s_sh[2 * u];
            f1 = bhi(v) * s_sc[2 * u + 1] + s_sh[2 * u + 1];
            *(float2*)&x3out[(size_t)m * 128 + 2 * u] = make_float2(f0, f1);
        }
        *(float2*)&Xs[r][2 * u] = make_float2(f0, f1);
    }
    __syncthreads();
    int r = tid >> 2;
    int cg = tid & 3;
    int cbase = cg * 10;
    float acc[10] = {};
    for (int k = 0; k < 128; k++) {
        float a = Xs[r][k];
#pragma unroll
        for (int j = 0; j < 10; j++) acc[j] += a * Ws[k * 40 + cbase + j];
    }
#pragma unroll
    for (int j = 0; j < 10; j++) acc[j] += linb[cbase + j];
    float m = acc[0];
#pragma unroll
    for (int j = 1; j < 10; j++) m = fmaxf(m, acc[j]);
    m = fmaxf(m, __shfl_xor(m, 1));
    m = fmaxf(m, __shfl_xor(m, 2));
    float ex[10];
    float s = 0.f;
#pragma unroll
    for (int j = 0; j < 10; j++) { ex[j] = expf(acc[j] - m); s += ex[j]; }
    s += __shfl_xor(s, 1);
    s += __shfl_xor(s, 2);
    float inv = 1.0f / s;
    int mrow = m0 + r;
    if (mrow < N_NODES) {
#pragma unroll
        for (int j = 0; j < 10; j += 2) {
            *(float2*)&logits[(size_t)mrow * 40 + cbase + j] = make_float2(acc[j], acc[j + 1]);
            *(float2*)&probs[(size_t)mrow * 40 + cbase + j] = make_float2(ex[j] * inv, ex[j + 1] * inv);
        }
    }
}

// ---------------------------------------------------------------------------
extern "C" void kernel_launch(void* const* d_in, const int* in_sizes, int n_in,
                              void* d_out, int out_size, void* d_ws, size_t ws_size,
                              hipStream_t stream) {
    const float* x = (const float*)d_in[0];
    const unsigned int* eidx = (const unsigned int*)d_in[1];
    const float* ew = (const float*)d_in[2];
    const float* W1 = (const float*)d_in[3];
    const float* b1 = (const float*)d_in[4];
    const float* W2 = (const float*)d_in[5];
    const float* b2 = (const float*)d_in[6];
    const float* W3 = (const float*)d_in[7];
    const float* b3 = (const float*)d_in[8];
    const float* g1 = (const float*)d_in[9];
    const float* be1 = (const float*)d_in[10];
    const float* g2 = (const float*)d_in[11];
    const float* be2 = (const float*)d_in[12];
    const float* g3 = (const float*)d_in[13];
    const float* be3 = (const float*)d_in[14];
    const float* linW = (const float*)d_in[15];
    const float* linb = (const float*)d_in[16];

    float* out = (float*)d_out;
    float* logits = out;
    float* probs = out + (size_t)N_NODES * NCLASS;
    float* x3out = out + 2 * (size_t)N_NODES * NCLASS;

    char* ws = (char*)d_ws;
    size_t off = 0;
    auto take = [&](size_t bytes) -> char* {
        char* p = ws + off;
        off += (bytes + 255) & ~(size_t)255;
        return p;
    };
    int* row32 = (int*)take((size_t)N_EDGES * 4);
    int* col32 = (int*)take((size_t)N_EDGES * 4);
    int* slot = (int*)take((size_t)N_EDGES * 4);
    int* colptr = (int*)take((size_t)(N_NODES + 1) * 4);
    int* counts = (int*)take((size_t)N_NODES * 4);
    unsigned long long* degcnt = (unsigned long long*)take((size_t)N_NODES * 8);
    int2* ern = (int2*)take((size_t)N_EDGES * 8);
    float* dinv = (float*)take((size_t)N_NODES * 4);
    unsigned short* hbuf = (unsigned short*)take((size_t)N_NODES * NHID * 2);
    unsigned short* abuf = (unsigned short*)take((size_t)N_NODES * NHID * 2);
    unsigned short* W1t = (unsigned short*)take((size_t)512 * 128 * 2);
    unsigned short* W2t = (unsigned short*)take((size_t)128 * 128 * 2);
    unsigned short* W3t = (unsigned short*)take((size_t)128 * 128 * 2);
    float* stats = (float*)take(768 * 4);   // [sums1|sumsq1|sums2|sumsq2|sums3|sumsq3]
    int* syncp = (int*)take(8 * 4);         // [0]=dinv ticket
    int* bsum = (int*)take((size_t)SCAN_BLOCKS * 4);
    int* bpre = (int*)take((size_t)SCAN_BLOCKS * 4);
    (void)ws_size; (void)n_in; (void)in_sizes; (void)out_size;

    float* sums1 = stats, *sumsq1 = stats + 128;
    float* sums2 = stats + 256, *sumsq2 = stats + 384;
    float* sums3 = stats + 512, *sumsq3 = stats + 640;

    const int TPB = 256;

    // preprocessing + layer-1 GEMM overlapped with edge histogram (fat, 512T)
    k_prep_w<<<(98304 + TPB - 1) / TPB, TPB, 0, stream>>>(W1, W2, W3, W1t, W2t, W3t, degcnt, stats, syncp);
    k_fat<<<GEMM1_BLOCKS + EDGE_BLOCKS_F, 512, 0, stream>>>(
        x, W1t, hbuf, eidx, ew, row32, col32, degcnt, slot);
    k_dinv<<<SCAN_BLOCKS, TPB, 0, stream>>>(degcnt, dinv, counts, bsum, &syncp[0], bpre, colptr);
    k_scan3<<<SCAN_BLOCKS, TPB, 0, stream>>>(counts, bpre, colptr);
    k_scatter<<<EDGE_BLOCKS, TPB, 0, stream>>>(row32, col32, ew, dinv, colptr, slot, ern);

    // layer 1
    k_aggregate<<<AGG_BLOCKS, TPB, 0, stream>>>((const unsigned int*)hbuf, colptr, ern, dinv, b1, (unsigned int*)abuf, 1);
    k_bnstats<<<BN_BLOCKS, TPB, 0, stream>>>((const unsigned int*)abuf, sums1, sumsq1);

    // layer 2 (BN1 applied inline in GEMM prologue from raw sums)
    k_gemm_h<<<GEMMH_BLOCKS, TPB, 0, stream>>>((const unsigned int*)abuf, W2t, sums1, sumsq1, g1, be1, hbuf);
    k_aggregate<<<AGG_BLOCKS, TPB, 0, stream>>>((const unsigned int*)hbuf, colptr, ern, dinv, b2, (unsigned int*)abuf, 1);
    k_bnstats<<<BN_BLOCKS, TPB, 0, stream>>>((const unsigned int*)abuf, sums2, sumsq2);

    // layer 3
    k_gemm_h<<<GEMMH_BLOCKS, TPB, 0, stream>>>((const unsigned int*)abuf, W3t, sums2, sumsq2, g2, be2, hbuf);
    k_aggregate<<<AGG_BLOCKS, TPB, 0, stream>>>((const unsigned int*)hbuf, colptr, ern, dinv, b3, (unsigned int*)abuf, 0);
    k_bnstats<<<BN_BLOCKS, TPB, 0, stream>>>((const unsigned int*)abuf, sums3, sumsq3);

    // head: BN3 apply (inline) + x3 write + logits + softmax
    k_logits<<<(N_NODES + 63) / 64, TPB, 0, stream>>>((const unsigned int*)abuf, sums3, sumsq3, g3, be3, linW, linb, logits, probs, x3out);
}

// Round 14
// 459.609 us; speedup vs baseline: 1.0387x; 1.0032x over previous
//
#include <hip/hip_runtime.h>
#include <hip/hip_bf16.h>

#define N_NODES 50000
#define N_EDGES 800000
#define NFEAT 512
#define NHID 128
#define NCLASS 40
#define BN_EPS 1e-5f

typedef __attribute__((ext_vector_type(8))) short short8;
typedef __attribute__((ext_vector_type(4))) float f32x4;

#define GEMM1_BLOCKS ((N_NODES + 127) / 128)   // 391 (BM=128 — proven best)
#define GEMMH_BLOCKS ((N_NODES + 127) / 128)   // 391
#define EDGE_BLOCKS ((N_EDGES + 255) / 256)    // 3125
#define SCAN_BLOCKS ((N_NODES + 255) / 256)    // 196
#define BN_BLOCKS ((N_NODES + 255) / 256)      // 196
#define AGG_BLOCKS ((N_NODES * 64 + 255) / 256) // 12500 (1 wave per node)

__device__ __forceinline__ unsigned short f2b(float f) {
    unsigned int u = __float_as_uint(f);
    u += 0x7fff + ((u >> 16) & 1);   // RTNE
    return (unsigned short)(u >> 16);
}
__device__ __forceinline__ unsigned int pk2(float lo, float hi) {
    unsigned int r;
    asm("v_cvt_pk_bf16_f32 %0, %1, %2" : "=v"(r) : "v"(lo), "v"(hi));
    return r;
}
__device__ __forceinline__ float blo(unsigned int v) {
    return __uint_as_float(v << 16);
}
__device__ __forceinline__ float bhi(unsigned int v) {
    return __uint_as_float(v & 0xffff0000u);
}

// ---------------------------------------------------------------------------
// Weight prep: fp32 W[K][128] -> bf16 W^T[128][K] for W1,W2,W3; zero degcnt,
// stats[768], sync[8].
__global__ void k_prep_w(const float* __restrict__ W1, const float* __restrict__ W2,
                         const float* __restrict__ W3, unsigned short* __restrict__ W1t,
                         unsigned short* __restrict__ W2t, unsigned short* __restrict__ W3t,
                         unsigned long long* __restrict__ degcnt,
                         float* __restrict__ stats, int* __restrict__ syncp) {
    int i = blockIdx.x * blockDim.x + threadIdx.x;
    if (i < N_NODES) degcnt[i] = 0ULL;
    if (i < 768) stats[i] = 0.f;
    else if (i < 776) syncp[i - 768] = 0;
    if (i < 65536) {
        int k = i >> 7, n = i & 127;
        W1t[n * 512 + k] = f2b(W1[i]);
    } else if (i < 81920) {
        int j = i - 65536; int k = j >> 7, n = j & 127;
        W2t[n * 128 + k] = f2b(W2[j]);
    } else if (i < 98304) {
        int j = i - 81920; int k = j >> 7, n = j & 127;
        W3t[n * 128 + k] = f2b(W3[j]);
    }
}

// ---------------------------------------------------------------------------
// FAT kernel — R7-proven 256T/4-wave form (62.6us). R13's 8-wave variant
// REGRESSED (70-85us at occ 38%): k_fat is bound by the per-block serial
// staging chain + edge-flood congestion, NOT wave count (occ 24-45% all
// land 62-85us). Blocks [0,391): GEMM BM=128 BK=32 K=512 w/ reg prefetch;
// blocks [391,391+3125): edge convert + histogram.
__global__ __launch_bounds__(256) void k_fat(
    const float* __restrict__ x, const unsigned short* __restrict__ W1t,
    unsigned short* __restrict__ hbuf,
    const unsigned int* __restrict__ words, const float* __restrict__ ew,
    int* __restrict__ row, int* __restrict__ col,
    unsigned long long* __restrict__ degcnt, int* __restrict__ slot) {
    __shared__ unsigned short As[128][40];
    __shared__ unsigned short Bs[128][40];
    __shared__ int s_any;
    int tid = threadIdx.x;
    if (blockIdx.x < GEMM1_BLOCKS) {
        int m0 = blockIdx.x * 128;
        int srow = tid >> 1;
        int skh = (tid & 1) << 4;
        int wave = tid >> 6, lane = tid & 63;
        int wm = (wave >> 1) * 64, wn = (wave & 1) * 64;
        int l15 = lane & 15, quad = lane >> 4;
        f32x4 acc[4][4] = {};
        bool arow_ok = (m0 + srow) < N_NODES;
        const float* arow_p = x + (size_t)(m0 + srow) * 512 + skh;
        const unsigned short* wrow_p = W1t + (size_t)srow * 512 + skh;
        float4 ta[4];
        uint4 tb0, tb1;
#pragma unroll
        for (int q = 0; q < 4; q++) {
            ta[q] = make_float4(0.f, 0.f, 0.f, 0.f);
            if (arow_ok) ta[q] = *(const float4*)(arow_p + q * 4);
        }
        tb0 = *(const uint4*)(wrow_p);
        tb1 = *(const uint4*)(wrow_p + 8);
        for (int kt = 0; kt < 512; kt += 32) {
            unsigned int p[8];
#pragma unroll
            for (int q = 0; q < 4; q++) {
                p[2 * q]     = pk2(ta[q].x, ta[q].y);
                p[2 * q + 1] = pk2(ta[q].z, ta[q].w);
            }
            *(uint4*)&As[srow][skh] = make_uint4(p[0], p[1], p[2], p[3]);
            *(uint4*)&As[srow][skh + 8] = make_uint4(p[4], p[5], p[6], p[7]);
            *(uint4*)&Bs[srow][skh] = tb0;
            *(uint4*)&Bs[srow][skh + 8] = tb1;
            __syncthreads();
            if (kt + 32 < 512) {   // prefetch next K-tile under ds_read+MFMA
#pragma unroll
                for (int q = 0; q < 4; q++) {
                    float4 t4 = make_float4(0.f, 0.f, 0.f, 0.f);
                    if (arow_ok) t4 = *(const float4*)(arow_p + kt + 32 + q * 4);
                    ta[q] = t4;
                }
                tb0 = *(const uint4*)(wrow_p + kt + 32);
                tb1 = *(const uint4*)(wrow_p + kt + 40);
            }
            short8 a[4], b[4];
#pragma unroll
            for (int i = 0; i < 4; i++) a[i] = *(const short8*)&As[wm + i * 16 + l15][quad * 8];
#pragma unroll
            for (int j = 0; j < 4; j++) b[j] = *(const short8*)&Bs[wn + j * 16 + l15][quad * 8];
#pragma unroll
            for (int i = 0; i < 4; i++)
#pragma unroll
                for (int j = 0; j < 4; j++)
                    acc[i][j] = __builtin_amdgcn_mfma_f32_16x16x32_bf16(a[i], b[j], acc[i][j], 0, 0, 0);
            __syncthreads();
        }
#pragma unroll
        for (int i = 0; i < 4; i++) {
            int mb = m0 + wm + i * 16 + quad * 4;
#pragma unroll
            for (int r = 0; r < 4; r++) {
                int m = mb + r;
                if (m < N_NODES) {
#pragma unroll
                    for (int j = 0; j < 4; j++)
                        hbuf[(size_t)m * 128 + wn + j * 16 + l15] = f2b(acc[i][j][r]);
                }
            }
        }
    } else {
        // ---- edge convert + degree histogram (per-block inline detect) ----
        if (tid == 0) s_any = 0;
        __syncthreads();
        unsigned int probe = words[2 * tid + 1];
        if (probe != 0) atomicAdd(&s_any, 1);
        __syncthreads();
        int f = (s_any == 0) ? 1 : 0;  // 1 => int64 layout
        int e = (blockIdx.x - GEMM1_BLOCKS) * 256 + tid;
        if (e < N_EDGES) {
            unsigned int r = f ? words[2 * (size_t)e] : words[e];
            unsigned int c = f ? words[2 * ((size_t)e + N_EDGES)] : words[e + N_EDGES];
            row[e] = (int)r;
            col[e] = (int)c;
            unsigned int q = __float2uint_rn(ew[e] * 8388608.0f);  // 2^23 fixed point
            unsigned long long old = atomicAdd(&degcnt[c], (1ULL << 32) | (unsigned long long)q);
            slot[e] = (int)(old >> 32);
        }
    }
}

// ---------------------------------------------------------------------------
// dinv + counts + scan phase-1 block reduction; LAST block (ticket) also
// scans the 196 block sums (one-shot arrivals, no polling).
__global__ __launch_bounds__(256) void k_dinv(const unsigned long long* __restrict__ degcnt,
                                              float* __restrict__ dinv,
                                              int* __restrict__ counts,
                                              int* __restrict__ bsum,
                                              int* __restrict__ ticket,
                                              int* __restrict__ bpre,
                                              int* __restrict__ colptr) {
    int i = blockIdx.x * 256 + threadIdx.x;
    int cnt = 0;
    if (i < N_NODES) {
        unsigned long long v = degcnt[i];
        float deg = 1.0f + (float)(unsigned int)(v & 0xffffffffULL) * (1.0f / 8388608.0f);
        dinv[i] = rsqrtf(deg);
        cnt = (int)(v >> 32);
        counts[i] = cnt;
    }
    __shared__ int sh[256];
    __shared__ int s_last;
    sh[threadIdx.x] = cnt;
    __syncthreads();
    for (int ofs = 128; ofs > 0; ofs >>= 1) {
        if (threadIdx.x < ofs) sh[threadIdx.x] += sh[threadIdx.x + ofs];
        __syncthreads();
    }
    if (threadIdx.x == 0) {
        bsum[blockIdx.x] = sh[0];
        __threadfence();
        int t = atomicAdd(ticket, 1);
        s_last = (t == SCAN_BLOCKS - 1) ? 1 : 0;
    }
    __syncthreads();
    if (s_last) {
        __threadfence();
        int t = threadIdx.x;
        int v = (t < SCAN_BLOCKS) ? ((volatile int*)bsum)[t] : 0;
        sh[t] = v;
        __syncthreads();
        for (int ofs = 1; ofs < 256; ofs <<= 1) {
            int u = (t >= ofs) ? sh[t - ofs] : 0;
            __syncthreads();
            sh[t] += u;
            __syncthreads();
        }
        if (t < SCAN_BLOCKS) bpre[t] = sh[t] - v;  // exclusive
        if (t == SCAN_BLOCKS - 1) colptr[N_NODES] = sh[t];
    }
}

__global__ __launch_bounds__(256) void k_scan3(const int* __restrict__ counts,
                                               const int* __restrict__ bpre,
                                               int* __restrict__ colptr) {
    int t = threadIdx.x;
    int i = blockIdx.x * 256 + t;
    int v = (i < N_NODES) ? counts[i] : 0;
    __shared__ int sh[256];
    sh[t] = v;
    __syncthreads();
    for (int ofs = 1; ofs < 256; ofs <<= 1) {
        int u = (t >= ofs) ? sh[t - ofs] : 0;
        __syncthreads();
        sh[t] += u;
        __syncthreads();
    }
    if (i < N_NODES) colptr[i] = bpre[blockIdx.x] + sh[t] - v;
}

// Atomic-free scatter into interleaved (row, norm) records.
__global__ void k_scatter(const int* __restrict__ row, const int* __restrict__ col,
                          const float* __restrict__ ew, const float* __restrict__ dinv,
                          const int* __restrict__ colptr, const int* __restrict__ slot,
                          int2* __restrict__ ern) {
    int e = blockIdx.x * blockDim.x + threadIdx.x;
    if (e < N_EDGES) {
        int c = col[e], r = row[e];
        int p = colptr[c] + slot[e];
        float nrm = dinv[r] * ew[e] * dinv[c];
        ern[p] = make_int2(r, __float_as_int(nrm));
    }
}

// ---------------------------------------------------------------------------
// CSR aggregation: ONE wave per node, 16-edge fully-batched rounds (clamped
// OOB slots with zero weight). Critical path = (#rounds) x gather latency;
// mean degree 16 -> 16-wide rounds halve the round count vs R7's 8-wide.
// Clamped slots hit ern[start] + one hot row (L1 broadcast) — near-free.
__global__ __launch_bounds__(256) void k_aggregate(
    const unsigned int* __restrict__ hb, const int* __restrict__ colptr,
    const int2* __restrict__ ern, const float* __restrict__ dinv,
    const float* __restrict__ bias, unsigned int* __restrict__ out, int relu) {
    int node = (blockIdx.x * blockDim.x + threadIdx.x) >> 6;
    int lane = threadIdx.x & 63;
    if (node >= N_NODES) return;
    float di = dinv[node];
    float selfw = di * di;
    unsigned int sv = hb[(size_t)node * 64 + lane];
    float a0 = selfw * blo(sv);
    float a1 = selfw * bhi(sv);
    float c0 = 0.f, c1 = 0.f;
    int start = colptr[node], end = colptr[node + 1];
    for (int e0 = start; e0 < end; e0 += 16) {
        int2 rw[16];
        float wq[16];
#pragma unroll
        for (int q = 0; q < 16; q++) {
            int ee = e0 + q;
            bool ok = ee < end;
            rw[q] = ern[ok ? ee : start];          // clamped, always valid
            wq[q] = ok ? __int_as_float(rw[q].y) : 0.f;
        }
        unsigned int v[16];
#pragma unroll
        for (int q = 0; q < 16; q++) v[q] = hb[(size_t)rw[q].x * 64 + lane];
#pragma unroll
        for (int q = 0; q < 16; q++) {
            if (q & 1) { c0 += wq[q] * blo(v[q]); c1 += wq[q] * bhi(v[q]); }
            else       { a0 += wq[q] * blo(v[q]); a1 += wq[q] * bhi(v[q]); }
        }
    }
    a0 += c0; a1 += c1;
    float2 bv = *(const float2*)&bias[2 * lane];
    a0 += bv.x;
    a1 += bv.y;
    if (relu) { a0 = fmaxf(a0, 0.f); a1 = fmaxf(a1, 0.f); }
    out[(size_t)node * 64 + lane] = pk2(a0, a1);
}

// ---------------------------------------------------------------------------
// BatchNorm stats: 4-row load batching (R7-proven). Buffers zeroed by prep.
__global__ __launch_bounds__(256) void k_bnstats(const unsigned int* __restrict__ x,
                                                 float* __restrict__ sums,
                                                 float* __restrict__ sumsq) {
    int u = threadIdx.x & 63;
    int strip = threadIdx.x >> 6;
    int r0 = blockIdx.x * 256;
    int rend = min(r0 + 256, N_NODES);
    float sl = 0.f, s2l = 0.f, sh_ = 0.f, s2h = 0.f;
    for (int r = r0 + strip; r < rend; r += 16) {
        unsigned int v[4];
#pragma unroll
        for (int k = 0; k < 4; k++) {
            int rr = r + 4 * k;
            v[k] = (rr < rend) ? x[(size_t)rr * 64 + u] : 0u;
        }
#pragma unroll
        for (int k = 0; k < 4; k++) {
            float a = blo(v[k]), b = bhi(v[k]);
            sl += a; s2l += a * a;
            sh_ += b; s2h += b * b;
        }
    }
    __shared__ float buf[4][64][4];
    buf[strip][u][0] = sl; buf[strip][u][1] = s2l;
    buf[strip][u][2] = sh_; buf[strip][u][3] = s2h;
    __syncthreads();
    if (strip == 0) {
#pragma unroll
        for (int s = 1; s < 4; s++) {
            sl += buf[s][u][0]; s2l += buf[s][u][1];
            sh_ += buf[s][u][2]; s2h += buf[s][u][3];
        }
        atomicAdd(&sums[2 * u], sl);
        atomicAdd(&sums[2 * u + 1], sh_);
        atomicAdd(&sumsq[2 * u], s2l);
        atomicAdd(&sumsq[2 * u + 1], s2h);
    }
}

// ---------------------------------------------------------------------------
// Layer-2/3 GEMM (R7-proven LDS version): A bf16-packed [M,64 uints], BN
// scale/shift computed inline in the prologue. K=128, reg prefetch.
__global__ __launch_bounds__(256) void k_gemm_h(
    const unsigned int* __restrict__ Ab, const unsigned short* __restrict__ Wt,
    const float* __restrict__ sums, const float* __restrict__ sumsq,
    const float* __restrict__ g, const float* __restrict__ be,
    unsigned short* __restrict__ Out) {
    __shared__ unsigned short As[128][40];
    __shared__ unsigned short Bs[128][40];
    __shared__ float s_sc[128], s_sh[128];
    int tid = threadIdx.x;
    int m0 = blockIdx.x * 128;
    if (tid < 128) {
        const float invn = 1.0f / (float)N_NODES;
        float mu = sums[tid] * invn;
        float var = sumsq[tid] * invn - mu * mu;
        float iv = rsqrtf(var + BN_EPS);
        float sc = g[tid] * iv;
        s_sc[tid] = sc;
        s_sh[tid] = be[tid] - mu * sc;
    }
    __syncthreads();
    int srow = tid >> 1;
    int skh = (tid & 1) << 4;
    int wave = tid >> 6, lane = tid & 63;
    int wm = (wave >> 1) * 64, wn = (wave & 1) * 64;
    int l15 = lane & 15, quad = lane >> 4;
    f32x4 acc[4][4] = {};
    bool arow_ok = (m0 + srow) < N_NODES;
    const unsigned int* arow_b = Ab + (size_t)(m0 + srow) * 64 + (skh >> 1);
    const unsigned short* wrow_p = Wt + (size_t)srow * 128 + skh;
    uint4 r0 = make_uint4(0, 0, 0, 0), r1 = make_uint4(0, 0, 0, 0);
    uint4 tb0, tb1;
    if (arow_ok) {
        r0 = *(const uint4*)(arow_b);
        r1 = *(const uint4*)(arow_b + 4);
    }
    tb0 = *(const uint4*)(wrow_p);
    tb1 = *(const uint4*)(wrow_p + 8);
    for (int kt = 0; kt < 128; kt += 32) {
        unsigned int raw[8] = {r0.x, r0.y, r0.z, r0.w, r1.x, r1.y, r1.z, r1.w};
        unsigned int p[8];
#pragma unroll
        for (int q = 0; q < 8; q++) {
            int ch = kt + skh + 2 * q;
            float f0 = blo(raw[q]) * s_sc[ch] + s_sh[ch];
            float f1 = bhi(raw[q]) * s_sc[ch + 1] + s_sh[ch + 1];
            p[q] = pk2(f0, f1);
        }
        *(uint4*)&As[srow][skh] = make_uint4(p[0], p[1], p[2], p[3]);
        *(uint4*)&As[srow][skh + 8] = make_uint4(p[4], p[5], p[6], p[7]);
        *(uint4*)&Bs[srow][skh] = tb0;
        *(uint4*)&Bs[srow][skh + 8] = tb1;
        __syncthreads();
        if (kt + 32 < 128) {   // prefetch next K-tile under ds_read+MFMA
            if (arow_ok) {
                r0 = *(const uint4*)(arow_b + ((kt + 32) >> 1));
                r1 = *(const uint4*)(arow_b + ((kt + 32) >> 1) + 4);
            }
            tb0 = *(const uint4*)(wrow_p + kt + 32);
            tb1 = *(const uint4*)(wrow_p + kt + 40);
        }
        short8 a[4], b[4];
#pragma unroll
        for (int i = 0; i < 4; i++) a[i] = *(const short8*)&As[wm + i * 16 + l15][quad * 8];
#pragma unroll
        for (int j = 0; j < 4; j++) b[j] = *(const short8*)&Bs[wn + j * 16 + l15][quad * 8];
#pragma unroll
        for (int i = 0; i < 4; i++)
#pragma unroll
            for (int j = 0; j < 4; j++)
                acc[i][j] = __builtin_amdgcn_mfma_f32_16x16x32_bf16(a[i], b[j], acc[i][j], 0, 0, 0);
        __syncthreads();
    }
#pragma unroll
    for (int i = 0; i < 4; i++) {
        int mb = m0 + wm + i * 16 + quad * 4;
#pragma unroll
        for (int r = 0; r < 4; r++) {
            int m = mb + r;
            if (m < N_NODES) {
#pragma unroll
                for (int j = 0; j < 4; j++)
                    Out[(size_t)m * 128 + wn + j * 16 + l15] = f2b(acc[i][j][r]);
            }
        }
    }
}

// ---------------------------------------------------------------------------
// Head: BN3 scale/shift from raw sums (inline), x3 fp32 write, logits+softmax.
__global__ __launch_bounds__(256) void k_logits(const unsigned int* __restrict__ abuf,
                                                const float* __restrict__ sums,
                                                const float* __restrict__ sumsq,
                                                const float* __restrict__ g,
                                                const float* __restrict__ be,
                                                const float* __restrict__ linW,
                                                const float* __restrict__ linb,
                                                float* __restrict__ logits,
                                                float* __restrict__ probs,
                                                float* __restrict__ x3out) {
    __shared__ float Xs[64][130];
    __shared__ float Ws[128 * 40];
    __shared__ float s_sc[128], s_sh[128];
    int tid = threadIdx.x;
    int m0 = blockIdx.x * 64;
    if (tid < 128) {
        const float invn = 1.0f / (float)N_NODES;
        float mu = sums[tid] * invn;
        float var = sumsq[tid] * invn - mu * mu;
        float iv = rsqrtf(var + BN_EPS);
        float sc = g[tid] * iv;
        s_sc[tid] = sc;
        s_sh[tid] = be[tid] - mu * sc;
    }
    for (int q = tid; q < 1280; q += 256)
        *(float4*)&Ws[q * 4] = *(const float4*)&linW[q * 4];
    __syncthreads();
    for (int q = tid; q < 4096; q += 256) {
        int r = q >> 6, u = q & 63;
        int m = m0 + r;
        float f0 = 0.f, f1 = 0.f;
        if (m < N_NODES) {
            unsigned int v = abuf[(size_t)m * 64 + u];
            f0 = blo(v) * s_sc[2 * u] + s_sh[2 * u];
            f1 = bhi(v) * s_sc[2 * u + 1] + s_sh[2 * u + 1];
            *(float2*)&x3out[(size_t)m * 128 + 2 * u] = make_float2(f0, f1);
        }
        *(float2*)&Xs[r][2 * u] = make_float2(f0, f1);
    }
    __syncthreads();
    int r = tid >> 2;
    int cg = tid & 3;
    int cbase = cg * 10;
    float acc[10] = {};
    for (int k = 0; k < 128; k++) {
        float a = Xs[r][k];
#pragma unroll
        for (int j = 0; j < 10; j++) acc[j] += a * Ws[k * 40 + cbase + j];
    }
#pragma unroll
    for (int j = 0; j < 10; j++) acc[j] += linb[cbase + j];
    float m = acc[0];
#pragma unroll
    for (int j = 1; j < 10; j++) m = fmaxf(m, acc[j]);
    m = fmaxf(m, __shfl_xor(m, 1));
    m = fmaxf(m, __shfl_xor(m, 2));
    float ex[10];
    float s = 0.f;
#pragma unroll
    for (int j = 0; j < 10; j++) { ex[j] = expf(acc[j] - m); s += ex[j]; }
    s += __shfl_xor(s, 1);
    s += __shfl_xor(s, 2);
    float inv = 1.0f / s;
    int mrow = m0 + r;
    if (mrow < N_NODES) {
#pragma unroll
        for (int j = 0; j < 10; j += 2) {
            *(float2*)&logits[(size_t)mrow * 40 + cbase + j] = make_float2(acc[j], acc[j + 1]);
            *(float2*)&probs[(size_t)mrow * 40 + cbase + j] = make_float2(ex[j] * inv, ex[j + 1] * inv);
        }
    }
}

// ---------------------------------------------------------------------------
extern "C" void kernel_launch(void* const* d_in, const int* in_sizes, int n_in,
                              void* d_out, int out_size, void* d_ws, size_t ws_size,
                              hipStream_t stream) {
    const float* x = (const float*)d_in[0];
    const unsigned int* eidx = (const unsigned int*)d_in[1];
    const float* ew = (const float*)d_in[2];
    const float* W1 = (const float*)d_in[3];
    const float* b1 = (const float*)d_in[4];
    const float* W2 = (const float*)d_in[5];
    const float* b2 = (const float*)d_in[6];
    const float* W3 = (const float*)d_in[7];
    const float* b3 = (const float*)d_in[8];
    const float* g1 = (const float*)d_in[9];
    const float* be1 = (const float*)d_in[10];
    const float* g2 = (const float*)d_in[11];
    const float* be2 = (const float*)d_in[12];
    const float* g3 = (const float*)d_in[13];
    const float* be3 = (const float*)d_in[14];
    const float* linW = (const float*)d_in[15];
    const float* linb = (const float*)d_in[16];

    float* out = (float*)d_out;
    float* logits = out;
    float* probs = out + (size_t)N_NODES * NCLASS;
    float* x3out = out + 2 * (size_t)N_NODES * NCLASS;

    char* ws = (char*)d_ws;
    size_t off = 0;
    auto take = [&](size_t bytes) -> char* {
        char* p = ws + off;
        off += (bytes + 255) & ~(size_t)255;
        return p;
    };
    int* row32 = (int*)take((size_t)N_EDGES * 4);
    int* col32 = (int*)take((size_t)N_EDGES * 4);
    int* slot = (int*)take((size_t)N_EDGES * 4);
    int* colptr = (int*)take((size_t)(N_NODES + 1) * 4);
    int* counts = (int*)take((size_t)N_NODES * 4);
    unsigned long long* degcnt = (unsigned long long*)take((size_t)N_NODES * 8);
    int2* ern = (int2*)take((size_t)N_EDGES * 8);
    float* dinv = (float*)take((size_t)N_NODES * 4);
    unsigned short* hbuf = (unsigned short*)take((size_t)N_NODES * NHID * 2);
    unsigned short* abuf = (unsigned short*)take((size_t)N_NODES * NHID * 2);
    unsigned short* W1t = (unsigned short*)take((size_t)512 * 128 * 2);
    unsigned short* W2t = (unsigned short*)take((size_t)128 * 128 * 2);
    unsigned short* W3t = (unsigned short*)take((size_t)128 * 128 * 2);
    float* stats = (float*)take(768 * 4);   // [sums1|sumsq1|sums2|sumsq2|sums3|sumsq3]
    int* syncp = (int*)take(8 * 4);         // [0]=dinv ticket
    int* bsum = (int*)take((size_t)SCAN_BLOCKS * 4);
    int* bpre = (int*)take((size_t)SCAN_BLOCKS * 4);
    (void)ws_size; (void)n_in; (void)in_sizes; (void)out_size;

    float* sums1 = stats, *sumsq1 = stats + 128;
    float* sums2 = stats + 256, *sumsq2 = stats + 384;
    float* sums3 = stats + 512, *sumsq3 = stats + 640;

    const int TPB = 256;

    // preprocessing + layer-1 GEMM overlapped with edge histogram (fat, 256T)
    k_prep_w<<<(98304 + TPB - 1) / TPB, TPB, 0, stream>>>(W1, W2, W3, W1t, W2t, W3t, degcnt, stats, syncp);
    k_fat<<<GEMM1_BLOCKS + EDGE_BLOCKS, TPB, 0, stream>>>(
        x, W1t, hbuf, eidx, ew, row32, col32, degcnt, slot);
    k_dinv<<<SCAN_BLOCKS, TPB, 0, stream>>>(degcnt, dinv, counts, bsum, &syncp[0], bpre, colptr);
    k_scan3<<<SCAN_BLOCKS, TPB, 0, stream>>>(counts, bpre, colptr);
    k_scatter<<<EDGE_BLOCKS, TPB, 0, stream>>>(row32, col32, ew, dinv, colptr, slot, ern);

    // layer 1
    k_aggregate<<<AGG_BLOCKS, TPB, 0, stream>>>((const unsigned int*)hbuf, colptr, ern, dinv, b1, (unsigned int*)abuf, 1);
    k_bnstats<<<BN_BLOCKS, TPB, 0, stream>>>((const unsigned int*)abuf, sums1, sumsq1);

    // layer 2 (BN1 applied inline in GEMM prologue from raw sums)
    k_gemm_h<<<GEMMH_BLOCKS, TPB, 0, stream>>>((const unsigned int*)abuf, W2t, sums1, sumsq1, g1, be1, hbuf);
    k_aggregate<<<AGG_BLOCKS, TPB, 0, stream>>>((const unsigned int*)hbuf, colptr, ern, dinv, b2, (unsigned int*)abuf, 1);
    k_bnstats<<<BN_BLOCKS, TPB, 0, stream>>>((const unsigned int*)abuf, sums2, sumsq2);

    // layer 3
    k_gemm_h<<<GEMMH_BLOCKS, TPB, 0, stream>>>((const unsigned int*)abuf, W3t, sums2, sumsq2, g2, be2, hbuf);
    k_aggregate<<<AGG_BLOCKS, TPB, 0, stream>>>((const unsigned int*)hbuf, colptr, ern, dinv, b3, (unsigned int*)abuf, 0);
    k_bnstats<<<BN_BLOCKS, TPB, 0, stream>>>((const unsigned int*)abuf, sums3, sumsq3);

    // head: BN3 apply (inline) + x3 write + logits + softmax
    k_logits<<<(N_NODES + 63) / 64, TPB, 0, stream>>>((const unsigned int*)abuf, sums3, sumsq3, g3, be3, linW, linb, logits, probs, x3out);
}

// Round 15
// 450.992 us; speedup vs baseline: 1.0585x; 1.0191x over previous
//
#include <hip/hip_runtime.h>
#include <hip/hip_bf16.h>

#define N_NODES 50000
#define N_EDGES 800000
#define NFEAT 512
#define NHID 128
#define NCLASS 40
#define BN_EPS 1e-5f

typedef __attribute__((ext_vector_type(8))) short short8;
typedef __attribute__((ext_vector_type(4))) float f32x4;

#define GEMM1_BLOCKS ((N_NODES + 127) / 128)   // 391 (BM=128 — proven best)
#define GEMMH_BLOCKS ((N_NODES + 127) / 128)   // 391
#define EDGE_BLOCKS ((N_EDGES + 255) / 256)    // 3125
#define SCAN_BLOCKS ((N_NODES + 255) / 256)    // 196
#define BN_BLOCKS ((N_NODES + 255) / 256)      // 196
#define AGG_BLOCKS ((N_NODES * 64 + 255) / 256) // 12500 (1 wave per node)

__device__ __forceinline__ unsigned short f2b(float f) {
    unsigned int u = __float_as_uint(f);
    u += 0x7fff + ((u >> 16) & 1);   // RTNE
    return (unsigned short)(u >> 16);
}
__device__ __forceinline__ unsigned int pk2(float lo, float hi) {
    unsigned int r;
    asm("v_cvt_pk_bf16_f32 %0, %1, %2" : "=v"(r) : "v"(lo), "v"(hi));
    return r;
}
__device__ __forceinline__ float blo(unsigned int v) {
    return __uint_as_float(v << 16);
}
__device__ __forceinline__ float bhi(unsigned int v) {
    return __uint_as_float(v & 0xffff0000u);
}

// ---------------------------------------------------------------------------
// Weight prep: fp32 W[K][128] -> bf16 W^T[128][K] for W1,W2,W3; zero degcnt,
// stats[768], sync[8].
__global__ void k_prep_w(const float* __restrict__ W1, const float* __restrict__ W2,
                         const float* __restrict__ W3, unsigned short* __restrict__ W1t,
                         unsigned short* __restrict__ W2t, unsigned short* __restrict__ W3t,
                         unsigned long long* __restrict__ degcnt,
                         float* __restrict__ stats, int* __restrict__ syncp) {
    int i = blockIdx.x * blockDim.x + threadIdx.x;
    if (i < N_NODES) degcnt[i] = 0ULL;
    if (i < 768) stats[i] = 0.f;
    else if (i < 776) syncp[i - 768] = 0;
    if (i < 65536) {
        int k = i >> 7, n = i & 127;
        W1t[n * 512 + k] = f2b(W1[i]);
    } else if (i < 81920) {
        int j = i - 65536; int k = j >> 7, n = j & 127;
        W2t[n * 128 + k] = f2b(W2[j]);
    } else if (i < 98304) {
        int j = i - 81920; int k = j >> 7, n = j & 127;
        W3t[n * 128 + k] = f2b(W3[j]);
    }
}

// ---------------------------------------------------------------------------
// FAT kernel — R7's 256T/4-wave tile with DOUBLE-BUFFERED LDS: one barrier
// per K-step (16 total) instead of two (32). At 1.5 GEMM-blocks/CU every
// barrier drain is exposed (no other wave to run), so halving drains should
// recover ~5-10us. LDS 41KB (edge blocks drop to 3/CU — hidden under GEMM).
__global__ __launch_bounds__(256) void k_fat(
    const float* __restrict__ x, const unsigned short* __restrict__ W1t,
    unsigned short* __restrict__ hbuf,
    const unsigned int* __restrict__ words, const float* __restrict__ ew,
    int* __restrict__ row, int* __restrict__ col,
    unsigned long long* __restrict__ degcnt, int* __restrict__ slot) {
    __shared__ unsigned short As[2][128][40];
    __shared__ unsigned short Bs[2][128][40];
    __shared__ int s_any;
    int tid = threadIdx.x;
    if (blockIdx.x < GEMM1_BLOCKS) {
        int m0 = blockIdx.x * 128;
        int srow = tid >> 1;
        int skh = (tid & 1) << 4;
        int wave = tid >> 6, lane = tid & 63;
        int wm = (wave >> 1) * 64, wn = (wave & 1) * 64;
        int l15 = lane & 15, quad = lane >> 4;
        f32x4 acc[4][4] = {};
        bool arow_ok = (m0 + srow) < N_NODES;
        const float* arow_p = x + (size_t)(m0 + srow) * 512 + skh;
        const unsigned short* wrow_p = W1t + (size_t)srow * 512 + skh;
        // prologue: tile 0 -> regs -> LDS[0]
        float4 ta[4];
        uint4 tb0, tb1;
#pragma unroll
        for (int q = 0; q < 4; q++) {
            ta[q] = make_float4(0.f, 0.f, 0.f, 0.f);
            if (arow_ok) ta[q] = *(const float4*)(arow_p + q * 4);
        }
        tb0 = *(const uint4*)(wrow_p);
        tb1 = *(const uint4*)(wrow_p + 8);
        {
            unsigned int p[8];
#pragma unroll
            for (int q = 0; q < 4; q++) {
                p[2 * q]     = pk2(ta[q].x, ta[q].y);
                p[2 * q + 1] = pk2(ta[q].z, ta[q].w);
            }
            *(uint4*)&As[0][srow][skh] = make_uint4(p[0], p[1], p[2], p[3]);
            *(uint4*)&As[0][srow][skh + 8] = make_uint4(p[4], p[5], p[6], p[7]);
            *(uint4*)&Bs[0][srow][skh] = tb0;
            *(uint4*)&Bs[0][srow][skh + 8] = tb1;
        }
        __syncthreads();
        int cur = 0;
        for (int kt = 0; kt < 512; kt += 32) {
            bool more = (kt + 32 < 512);
            if (more) {   // prefetch next K-tile into regs (flies under MFMA)
#pragma unroll
                for (int q = 0; q < 4; q++) {
                    float4 t4 = make_float4(0.f, 0.f, 0.f, 0.f);
                    if (arow_ok) t4 = *(const float4*)(arow_p + kt + 32 + q * 4);
                    ta[q] = t4;
                }
                tb0 = *(const uint4*)(wrow_p + kt + 32);
                tb1 = *(const uint4*)(wrow_p + kt + 40);
            }
            short8 a[4], b[4];
#pragma unroll
            for (int i = 0; i < 4; i++) a[i] = *(const short8*)&As[cur][wm + i * 16 + l15][quad * 8];
#pragma unroll
            for (int j = 0; j < 4; j++) b[j] = *(const short8*)&Bs[cur][wn + j * 16 + l15][quad * 8];
#pragma unroll
            for (int i = 0; i < 4; i++)
#pragma unroll
                for (int j = 0; j < 4; j++)
                    acc[i][j] = __builtin_amdgcn_mfma_f32_16x16x32_bf16(a[i], b[j], acc[i][j], 0, 0, 0);
            if (more) {   // write next tile into the idle buffer
                unsigned int p[8];
#pragma unroll
                for (int q = 0; q < 4; q++) {
                    p[2 * q]     = pk2(ta[q].x, ta[q].y);
                    p[2 * q + 1] = pk2(ta[q].z, ta[q].w);
                }
                int nxt = cur ^ 1;
                *(uint4*)&As[nxt][srow][skh] = make_uint4(p[0], p[1], p[2], p[3]);
                *(uint4*)&As[nxt][srow][skh + 8] = make_uint4(p[4], p[5], p[6], p[7]);
                *(uint4*)&Bs[nxt][srow][skh] = tb0;
                *(uint4*)&Bs[nxt][srow][skh + 8] = tb1;
            }
            __syncthreads();
            cur ^= 1;
        }
#pragma unroll
        for (int i = 0; i < 4; i++) {
            int mb = m0 + wm + i * 16 + quad * 4;
#pragma unroll
            for (int r = 0; r < 4; r++) {
                int m = mb + r;
                if (m < N_NODES) {
#pragma unroll
                    for (int j = 0; j < 4; j++)
                        hbuf[(size_t)m * 128 + wn + j * 16 + l15] = f2b(acc[i][j][r]);
                }
            }
        }
    } else {
        // ---- edge convert + degree histogram (per-block inline detect) ----
        if (tid == 0) s_any = 0;
        __syncthreads();
        unsigned int probe = words[2 * tid + 1];
        if (probe != 0) atomicAdd(&s_any, 1);
        __syncthreads();
        int f = (s_any == 0) ? 1 : 0;  // 1 => int64 layout
        int e = (blockIdx.x - GEMM1_BLOCKS) * 256 + tid;
        if (e < N_EDGES) {
            unsigned int r = f ? words[2 * (size_t)e] : words[e];
            unsigned int c = f ? words[2 * ((size_t)e + N_EDGES)] : words[e + N_EDGES];
            row[e] = (int)r;
            col[e] = (int)c;
            unsigned int q = __float2uint_rn(ew[e] * 8388608.0f);  // 2^23 fixed point
            unsigned long long old = atomicAdd(&degcnt[c], (1ULL << 32) | (unsigned long long)q);
            slot[e] = (int)(old >> 32);
        }
    }
}

// ---------------------------------------------------------------------------
// dinv + counts + scan phase-1 block reduction; LAST block (ticket) also
// scans the 196 block sums (one-shot arrivals, no polling).
__global__ __launch_bounds__(256) void k_dinv(const unsigned long long* __restrict__ degcnt,
                                              float* __restrict__ dinv,
                                              int* __restrict__ counts,
                                              int* __restrict__ bsum,
                                              int* __restrict__ ticket,
                                              int* __restrict__ bpre,
                                              int* __restrict__ colptr) {
    int i = blockIdx.x * 256 + threadIdx.x;
    int cnt = 0;
    if (i < N_NODES) {
        unsigned long long v = degcnt[i];
        float deg = 1.0f + (float)(unsigned int)(v & 0xffffffffULL) * (1.0f / 8388608.0f);
        dinv[i] = rsqrtf(deg);
        cnt = (int)(v >> 32);
        counts[i] = cnt;
    }
    __shared__ int sh[256];
    __shared__ int s_last;
    sh[threadIdx.x] = cnt;
    __syncthreads();
    for (int ofs = 128; ofs > 0; ofs >>= 1) {
        if (threadIdx.x < ofs) sh[threadIdx.x] += sh[threadIdx.x + ofs];
        __syncthreads();
    }
    if (threadIdx.x == 0) {
        bsum[blockIdx.x] = sh[0];
        __threadfence();
        int t = atomicAdd(ticket, 1);
        s_last = (t == SCAN_BLOCKS - 1) ? 1 : 0;
    }
    __syncthreads();
    if (s_last) {
        __threadfence();
        int t = threadIdx.x;
        int v = (t < SCAN_BLOCKS) ? ((volatile int*)bsum)[t] : 0;
        sh[t] = v;
        __syncthreads();
        for (int ofs = 1; ofs < 256; ofs <<= 1) {
            int u = (t >= ofs) ? sh[t - ofs] : 0;
            __syncthreads();
            sh[t] += u;
            __syncthreads();
        }
        if (t < SCAN_BLOCKS) bpre[t] = sh[t] - v;  // exclusive
        if (t == SCAN_BLOCKS - 1) colptr[N_NODES] = sh[t];
    }
}

__global__ __launch_bounds__(256) void k_scan3(const int* __restrict__ counts,
                                               const int* __restrict__ bpre,
                                               int* __restrict__ colptr) {
    int t = threadIdx.x;
    int i = blockIdx.x * 256 + t;
    int v = (i < N_NODES) ? counts[i] : 0;
    __shared__ int sh[256];
    sh[t] = v;
    __syncthreads();
    for (int ofs = 1; ofs < 256; ofs <<= 1) {
        int u = (t >= ofs) ? sh[t - ofs] : 0;
        __syncthreads();
        sh[t] += u;
        __syncthreads();
    }
    if (i < N_NODES) colptr[i] = bpre[blockIdx.x] + sh[t] - v;
}

// Atomic-free scatter into interleaved (row, norm) records.
__global__ void k_scatter(const int* __restrict__ row, const int* __restrict__ col,
                          const float* __restrict__ ew, const float* __restrict__ dinv,
                          const int* __restrict__ colptr, const int* __restrict__ slot,
                          int2* __restrict__ ern) {
    int e = blockIdx.x * blockDim.x + threadIdx.x;
    if (e < N_EDGES) {
        int c = col[e], r = row[e];
        int p = colptr[c] + slot[e];
        float nrm = dinv[r] * ew[e] * dinv[c];
        ern[p] = make_int2(r, __float_as_int(nrm));
    }
}

// ---------------------------------------------------------------------------
// CSR aggregation: ONE wave per node, 8-edge fully-batched rounds (clamped
// OOB slots with zero weight — no serial tail). R7-proven optimum: 16-wide
// batching (R14) was neutral-to-worse (more clamp waste); 2-wave split (R3)
// and node-serial (R2) regressed. Bound by cross-XCD L3 gather traffic
// (hbuf 12.8MB > 4MB per-XCD L2).
__global__ __launch_bounds__(256) void k_aggregate(
    const unsigned int* __restrict__ hb, const int* __restrict__ colptr,
    const int2* __restrict__ ern, const float* __restrict__ dinv,
    const float* __restrict__ bias, unsigned int* __restrict__ out, int relu) {
    int node = (blockIdx.x * blockDim.x + threadIdx.x) >> 6;
    int lane = threadIdx.x & 63;
    if (node >= N_NODES) return;
    float di = dinv[node];
    float selfw = di * di;
    unsigned int sv = hb[(size_t)node * 64 + lane];
    float a0 = selfw * blo(sv);
    float a1 = selfw * bhi(sv);
    float c0 = 0.f, c1 = 0.f;
    int start = colptr[node], end = colptr[node + 1];
    for (int e0 = start; e0 < end; e0 += 8) {
        int2 rw[8];
        float wq[8];
#pragma unroll
        for (int q = 0; q < 8; q++) {
            int ee = e0 + q;
            bool ok = ee < end;
            rw[q] = ern[ok ? ee : start];          // clamped, always valid
            wq[q] = ok ? __int_as_float(rw[q].y) : 0.f;
        }
        unsigned int v[8];
#pragma unroll
        for (int q = 0; q < 8; q++) v[q] = hb[(size_t)rw[q].x * 64 + lane];
#pragma unroll
        for (int q = 0; q < 8; q++) {
            if (q & 1) { c0 += wq[q] * blo(v[q]); c1 += wq[q] * bhi(v[q]); }
            else       { a0 += wq[q] * blo(v[q]); a1 += wq[q] * bhi(v[q]); }
        }
    }
    a0 += c0; a1 += c1;
    float2 bv = *(const float2*)&bias[2 * lane];
    a0 += bv.x;
    a1 += bv.y;
    if (relu) { a0 = fmaxf(a0, 0.f); a1 = fmaxf(a1, 0.f); }
    out[(size_t)node * 64 + lane] = pk2(a0, a1);
}

// ---------------------------------------------------------------------------
// BatchNorm stats: 4-row load batching (R7-proven). Buffers zeroed by prep.
__global__ __launch_bounds__(256) void k_bnstats(const unsigned int* __restrict__ x,
                                                 float* __restrict__ sums,
                                                 float* __restrict__ sumsq) {
    int u = threadIdx.x & 63;
    int strip = threadIdx.x >> 6;
    int r0 = blockIdx.x * 256;
    int rend = min(r0 + 256, N_NODES);
    float sl = 0.f, s2l = 0.f, sh_ = 0.f, s2h = 0.f;
    for (int r = r0 + strip; r < rend; r += 16) {
        unsigned int v[4];
#pragma unroll
        for (int k = 0; k < 4; k++) {
            int rr = r + 4 * k;
            v[k] = (rr < rend) ? x[(size_t)rr * 64 + u] : 0u;
        }
#pragma unroll
        for (int k = 0; k < 4; k++) {
            float a = blo(v[k]), b = bhi(v[k]);
            sl += a; s2l += a * a;
            sh_ += b; s2h += b * b;
        }
    }
    __shared__ float buf[4][64][4];
    buf[strip][u][0] = sl; buf[strip][u][1] = s2l;
    buf[strip][u][2] = sh_; buf[strip][u][3] = s2h;
    __syncthreads();
    if (strip == 0) {
#pragma unroll
        for (int s = 1; s < 4; s++) {
            sl += buf[s][u][0]; s2l += buf[s][u][1];
            sh_ += buf[s][u][2]; s2h += buf[s][u][3];
        }
        atomicAdd(&sums[2 * u], sl);
        atomicAdd(&sums[2 * u + 1], sh_);
        atomicAdd(&sumsq[2 * u], s2l);
        atomicAdd(&sumsq[2 * u + 1], s2h);
    }
}

// ---------------------------------------------------------------------------
// Layer-2/3 GEMM (R7-proven LDS version): A bf16-packed [M,64 uints], BN
// scale/shift computed inline in the prologue. K=128, reg prefetch.
__global__ __launch_bounds__(256) void k_gemm_h(
    const unsigned int* __restrict__ Ab, const unsigned short* __restrict__ Wt,
    const float* __restrict__ sums, const float* __restrict__ sumsq,
    const float* __restrict__ g, const float* __restrict__ be,
    unsigned short* __restrict__ Out) {
    __shared__ unsigned short As[128][40];
    __shared__ unsigned short Bs[128][40];
    __shared__ float s_sc[128], s_sh[128];
    int tid = threadIdx.x;
    int m0 = blockIdx.x * 128;
    if (tid < 128) {
        const float invn = 1.0f / (float)N_NODES;
        float mu = sums[tid] * invn;
        float var = sumsq[tid] * invn - mu * mu;
        float iv = rsqrtf(var + BN_EPS);
        float sc = g[tid] * iv;
        s_sc[tid] = sc;
        s_sh[tid] = be[tid] - mu * sc;
    }
    __syncthreads();
    int srow = tid >> 1;
    int skh = (tid & 1) << 4;
    int wave = tid >> 6, lane = tid & 63;
    int wm = (wave >> 1) * 64, wn = (wave & 1) * 64;
    int l15 = lane & 15, quad = lane >> 4;
    f32x4 acc[4][4] = {};
    bool arow_ok = (m0 + srow) < N_NODES;
    const unsigned int* arow_b = Ab + (size_t)(m0 + srow) * 64 + (skh >> 1);
    const unsigned short* wrow_p = Wt + (size_t)srow * 128 + skh;
    uint4 r0 = make_uint4(0, 0, 0, 0), r1 = make_uint4(0, 0, 0, 0);
    uint4 tb0, tb1;
    if (arow_ok) {
        r0 = *(const uint4*)(arow_b);
        r1 = *(const uint4*)(arow_b + 4);
    }
    tb0 = *(const uint4*)(wrow_p);
    tb1 = *(const uint4*)(wrow_p + 8);
    for (int kt = 0; kt < 128; kt += 32) {
        unsigned int raw[8] = {r0.x, r0.y, r0.z, r0.w, r1.x, r1.y, r1.z, r1.w};
        unsigned int p[8];
#pragma unroll
        for (int q = 0; q < 8; q++) {
            int ch = kt + skh + 2 * q;
            float f0 = blo(raw[q]) * s_sc[ch] + s_sh[ch];
            float f1 = bhi(raw[q]) * s_sc[ch + 1] + s_sh[ch + 1];
            p[q] = pk2(f0, f1);
        }
        *(uint4*)&As[srow][skh] = make_uint4(p[0], p[1], p[2], p[3]);
        *(uint4*)&As[srow][skh + 8] = make_uint4(p[4], p[5], p[6], p[7]);
        *(uint4*)&Bs[srow][skh] = tb0;
        *(uint4*)&Bs[srow][skh + 8] = tb1;
        __syncthreads();
        if (kt + 32 < 128) {   // prefetch next K-tile under ds_read+MFMA
            if (arow_ok) {
                r0 = *(const uint4*)(arow_b + ((kt + 32) >> 1));
                r1 = *(const uint4*)(arow_b + ((kt + 32) >> 1) + 4);
            }
            tb0 = *(const uint4*)(wrow_p + kt + 32);
            tb1 = *(const uint4*)(wrow_p + kt + 40);
        }
        short8 a[4], b[4];
#pragma unroll
        for (int i = 0; i < 4; i++) a[i] = *(const short8*)&As[wm + i * 16 + l15][quad * 8];
#pragma unroll
        for (int j = 0; j < 4; j++) b[j] = *(const short8*)&Bs[wn + j * 16 + l15][quad * 8];
#pragma unroll
        for (int i = 0; i < 4; i++)
#pragma unroll
            for (int j = 0; j < 4; j++)
                acc[i][j] = __builtin_amdgcn_mfma_f32_16x16x32_bf16(a[i], b[j], acc[i][j], 0, 0, 0);
        __syncthreads();
    }
#pragma unroll
    for (int i = 0; i < 4; i++) {
        int mb = m0 + wm + i * 16 + quad * 4;
#pragma unroll
        for (int r = 0; r < 4; r++) {
            int m = mb + r;
            if (m < N_NODES) {
#pragma unroll
                for (int j = 0; j < 4; j++)
                    Out[(size_t)m * 128 + wn + j * 16 + l15] = f2b(acc[i][j][r]);
            }
        }
    }
}

// ---------------------------------------------------------------------------
// Head: BN3 scale/shift from raw sums (inline), x3 fp32 write, logits+softmax.
__global__ __launch_bounds__(256) void k_logits(const unsigned int* __restrict__ abuf,
                                                const float* __restrict__ sums,
                                                const float* __restrict__ sumsq,
                                                const float* __restrict__ g,
                                                const float* __restrict__ be,
                                                const float* __restrict__ linW,
                                                const float* __restrict__ linb,
                                                float* __restrict__ logits,
                                                float* __restrict__ probs,
                                                float* __restrict__ x3out) {
    __shared__ float Xs[64][130];
    __shared__ float Ws[128 * 40];
    __shared__ float s_sc[128], s_sh[128];
    int tid = threadIdx.x;
    int m0 = blockIdx.x * 64;
    if (tid < 128) {
        const float invn = 1.0f / (float)N_NODES;
        float mu = sums[tid] * invn;
        float var = sumsq[tid] * invn - mu * mu;
        float iv = rsqrtf(var + BN_EPS);
        float sc = g[tid] * iv;
        s_sc[tid] = sc;
        s_sh[tid] = be[tid] - mu * sc;
    }
    for (int q = tid; q < 1280; q += 256)
        *(float4*)&Ws[q * 4] = *(const float4*)&linW[q * 4];
    __syncthreads();
    for (int q = tid; q < 4096; q += 256) {
        int r = q >> 6, u = q & 63;
        int m = m0 + r;
        float f0 = 0.f, f1 = 0.f;
        if (m < N_NODES) {
            unsigned int v = abuf[(size_t)m * 64 + u];
            f0 = blo(v) * s_sc[2 * u] + s_sh[2 * u];
            f1 = bhi(v) * s_sc[2 * u + 1] + s_sh[2 * u + 1];
            *(float2*)&x3out[(size_t)m * 128 + 2 * u] = make_float2(f0, f1);
        }
        *(float2*)&Xs[r][2 * u] = make_float2(f0, f1);
    }
    __syncthreads();
    int r = tid >> 2;
    int cg = tid & 3;
    int cbase = cg * 10;
    float acc[10] = {};
    for (int k = 0; k < 128; k++) {
        float a = Xs[r][k];
#pragma unroll
        for (int j = 0; j < 10; j++) acc[j] += a * Ws[k * 40 + cbase + j];
    }
#pragma unroll
    for (int j = 0; j < 10; j++) acc[j] += linb[cbase + j];
    float m = acc[0];
#pragma unroll
    for (int j = 1; j < 10; j++) m = fmaxf(m, acc[j]);
    m = fmaxf(m, __shfl_xor(m, 1));
    m = fmaxf(m, __shfl_xor(m, 2));
    float ex[10];
    float s = 0.f;
#pragma unroll
    for (int j = 0; j < 10; j++) { ex[j] = expf(acc[j] - m); s += ex[j]; }
    s += __shfl_xor(s, 1);
    s += __shfl_xor(s, 2);
    float inv = 1.0f / s;
    int mrow = m0 + r;
    if (mrow < N_NODES) {
#pragma unroll
        for (int j = 0; j < 10; j += 2) {
            *(float2*)&logits[(size_t)mrow * 40 + cbase + j] = make_float2(acc[j], acc[j + 1]);
            *(float2*)&probs[(size_t)mrow * 40 + cbase + j] = make_float2(ex[j] * inv, ex[j + 1] * inv);
        }
    }
}

// ---------------------------------------------------------------------------
extern "C" void kernel_launch(void* const* d_in, const int* in_sizes, int n_in,
                              void* d_out, int out_size, void* d_ws, size_t ws_size,
                              hipStream_t stream) {
    const float* x = (const float*)d_in[0];
    const unsigned int* eidx = (const unsigned int*)d_in[1];
    const float* ew = (const float*)d_in[2];
    const float* W1 = (const float*)d_in[3];
    const float* b1 = (const float*)d_in[4];
    const float* W2 = (const float*)d_in[5];
    const float* b2 = (const float*)d_in[6];
    const float* W3 = (const float*)d_in[7];
    const float* b3 = (const float*)d_in[8];
    const float* g1 = (const float*)d_in[9];
    const float* be1 = (const float*)d_in[10];
    const float* g2 = (const float*)d_in[11];
    const float* be2 = (const float*)d_in[12];
    const float* g3 = (const float*)d_in[13];
    const float* be3 = (const float*)d_in[14];
    const float* linW = (const float*)d_in[15];
    const float* linb = (const float*)d_in[16];

    float* out = (float*)d_out;
    float* logits = out;
    float* probs = out + (size_t)N_NODES * NCLASS;
    float* x3out = out + 2 * (size_t)N_NODES * NCLASS;

    char* ws = (char*)d_ws;
    size_t off = 0;
    auto take = [&](size_t bytes) -> char* {
        char* p = ws + off;
        off += (bytes + 255) & ~(size_t)255;
        return p;
    };
    int* row32 = (int*)take((size_t)N_EDGES * 4);
    int* col32 = (int*)take((size_t)N_EDGES * 4);
    int* slot = (int*)take((size_t)N_EDGES * 4);
    int* colptr = (int*)take((size_t)(N_NODES + 1) * 4);
    int* counts = (int*)take((size_t)N_NODES * 4);
    unsigned long long* degcnt = (unsigned long long*)take((size_t)N_NODES * 8);
    int2* ern = (int2*)take((size_t)N_EDGES * 8);
    float* dinv = (float*)take((size_t)N_NODES * 4);
    unsigned short* hbuf = (unsigned short*)take((size_t)N_NODES * NHID * 2);
    unsigned short* abuf = (unsigned short*)take((size_t)N_NODES * NHID * 2);
    unsigned short* W1t = (unsigned short*)take((size_t)512 * 128 * 2);
    unsigned short* W2t = (unsigned short*)take((size_t)128 * 128 * 2);
    unsigned short* W3t = (unsigned short*)take((size_t)128 * 128 * 2);
    float* stats = (float*)take(768 * 4);   // [sums1|sumsq1|sums2|sumsq2|sums3|sumsq3]
    int* syncp = (int*)take(8 * 4);         // [0]=dinv ticket
    int* bsum = (int*)take((size_t)SCAN_BLOCKS * 4);
    int* bpre = (int*)take((size_t)SCAN_BLOCKS * 4);
    (void)ws_size; (void)n_in; (void)in_sizes; (void)out_size;

    float* sums1 = stats, *sumsq1 = stats + 128;
    float* sums2 = stats + 256, *sumsq2 = stats + 384;
    float* sums3 = stats + 512, *sumsq3 = stats + 640;

    const int TPB = 256;

    // preprocessing + layer-1 GEMM overlapped with edge histogram (fat)
    k_prep_w<<<(98304 + TPB - 1) / TPB, TPB, 0, stream>>>(W1, W2, W3, W1t, W2t, W3t, degcnt, stats, syncp);
    k_fat<<<GEMM1_BLOCKS + EDGE_BLOCKS, TPB, 0, stream>>>(
        x, W1t, hbuf, eidx, ew, row32, col32, degcnt, slot);
    k_dinv<<<SCAN_BLOCKS, TPB, 0, stream>>>(degcnt, dinv, counts, bsum, &syncp[0], bpre, colptr);
    k_scan3<<<SCAN_BLOCKS, TPB, 0, stream>>>(counts, bpre, colptr);
    k_scatter<<<EDGE_BLOCKS, TPB, 0, stream>>>(row32, col32, ew, dinv, colptr, slot, ern);

    // layer 1
    k_aggregate<<<AGG_BLOCKS, TPB, 0, stream>>>((const unsigned int*)hbuf, colptr, ern, dinv, b1, (unsigned int*)abuf, 1);
    k_bnstats<<<BN_BLOCKS, TPB, 0, stream>>>((const unsigned int*)abuf, sums1, sumsq1);

    // layer 2 (BN1 applied inline in GEMM prologue from raw sums)
    k_gemm_h<<<GEMMH_BLOCKS, TPB, 0, stream>>>((const unsigned int*)abuf, W2t, sums1, sumsq1, g1, be1, hbuf);
    k_aggregate<<<AGG_BLOCKS, TPB, 0, stream>>>((const unsigned int*)hbuf, colptr, ern, dinv, b2, (unsigned int*)abuf, 1);
    k_bnstats<<<BN_BLOCKS, TPB, 0, stream>>>((const unsigned int*)abuf, sums2, sumsq2);

    // layer 3
    k_gemm_h<<<GEMMH_BLOCKS, TPB, 0, stream>>>((const unsigned int*)abuf, W3t, sums2, sumsq2, g2, be2, hbuf);
    k_aggregate<<<AGG_BLOCKS, TPB, 0, stream>>>((const unsigned int*)hbuf, colptr, ern, dinv, b3, (unsigned int*)abuf, 0);
    k_bnstats<<<BN_BLOCKS, TPB, 0, stream>>>((const unsigned int*)abuf, sums3, sumsq3);

    // head: BN3 apply (inline) + x3 write + logits + softmax
    k_logits<<<(N_NODES + 63) / 64, TPB, 0, stream>>>((const unsigned int*)abuf, sums3, sumsq3, g3, be3, linW, linb, logits, probs, x3out);
}

// Round 16
// 437.727 us; speedup vs baseline: 1.0906x; 1.0303x over previous
//
#include <hip/hip_runtime.h>
#include <hip/hip_bf16.h>

#define N_NODES 50000
#define N_EDGES 800000
#define NFEAT 512
#define NHID 128
#define NCLASS 40
#define BN_EPS 1e-5f

typedef __attribute__((ext_vector_type(8))) short short8;
typedef __attribute__((ext_vector_type(4))) float f32x4;

#define GEMM1_BLOCKS ((N_NODES + 127) / 128)   // 391 (BM=128 — proven best)
#define GEMMH_BLOCKS ((N_NODES + 127) / 128)   // 391
#define EDGE_BLOCKS ((N_EDGES + 255) / 256)    // 3125
#define SCAN_BLOCKS ((N_NODES + 255) / 256)    // 196
#define AGG_BLOCKS (N_NODES / 4)               // 12500 (exact: 4 nodes/block)
#define NREP 64                                // replicated BN stat buffers

__device__ __forceinline__ unsigned short f2b(float f) {
    unsigned int u = __float_as_uint(f);
    u += 0x7fff + ((u >> 16) & 1);   // RTNE
    return (unsigned short)(u >> 16);
}
__device__ __forceinline__ unsigned int pk2(float lo, float hi) {
    unsigned int r;
    asm("v_cvt_pk_bf16_f32 %0, %1, %2" : "=v"(r) : "v"(lo), "v"(hi));
    return r;
}
__device__ __forceinline__ float blo(unsigned int v) {
    return __uint_as_float(v << 16);
}
__device__ __forceinline__ float bhi(unsigned int v) {
    return __uint_as_float(v & 0xffff0000u);
}

// ---------------------------------------------------------------------------
// Weight prep: fp32 W[K][128] -> bf16 W^T[128][K] for W1,W2,W3; zero degcnt,
// the replicated stats buffers (3 layers x 2 arrays x 64 reps x 128 ch =
// 49152 floats) and sync[8].
__global__ void k_prep_w(const float* __restrict__ W1, const float* __restrict__ W2,
                         const float* __restrict__ W3, unsigned short* __restrict__ W1t,
                         unsigned short* __restrict__ W2t, unsigned short* __restrict__ W3t,
                         unsigned long long* __restrict__ degcnt,
                         float* __restrict__ stats, int* __restrict__ syncp) {
    int i = blockIdx.x * blockDim.x + threadIdx.x;
    if (i < N_NODES) degcnt[i] = 0ULL;
    if (i < 49152) stats[i] = 0.f;
    else if (i < 49160) syncp[i - 49152] = 0;
    if (i < 65536) {
        int k = i >> 7, n = i & 127;
        W1t[n * 512 + k] = f2b(W1[i]);
    } else if (i < 81920) {
        int j = i - 65536; int k = j >> 7, n = j & 127;
        W2t[n * 128 + k] = f2b(W2[j]);
    } else if (i < 98304) {
        int j = i - 81920; int k = j >> 7, n = j & 127;
        W3t[n * 128 + k] = f2b(W3[j]);
    }
}

// ---------------------------------------------------------------------------
// FAT kernel — double-buffered LDS GEMM (R15-measured, = best total 451us).
// k_fat is invariant ~62us across 8 structural variants; floor = mixed
// GEMM+edge execution sharing CU issue slots. Blocks [0,391): GEMM BM=128
// BK=32 K=512; blocks [391,391+3125): edge convert + histogram.
__global__ __launch_bounds__(256) void k_fat(
    const float* __restrict__ x, const unsigned short* __restrict__ W1t,
    unsigned short* __restrict__ hbuf,
    const unsigned int* __restrict__ words, const float* __restrict__ ew,
    int* __restrict__ row, int* __restrict__ col,
    unsigned long long* __restrict__ degcnt, int* __restrict__ slot) {
    __shared__ unsigned short As[2][128][40];
    __shared__ unsigned short Bs[2][128][40];
    __shared__ int s_any;
    int tid = threadIdx.x;
    if (blockIdx.x < GEMM1_BLOCKS) {
        int m0 = blockIdx.x * 128;
        int srow = tid >> 1;
        int skh = (tid & 1) << 4;
        int wave = tid >> 6, lane = tid & 63;
        int wm = (wave >> 1) * 64, wn = (wave & 1) * 64;
        int l15 = lane & 15, quad = lane >> 4;
        f32x4 acc[4][4] = {};
        bool arow_ok = (m0 + srow) < N_NODES;
        const float* arow_p = x + (size_t)(m0 + srow) * 512 + skh;
        const unsigned short* wrow_p = W1t + (size_t)srow * 512 + skh;
        float4 ta[4];
        uint4 tb0, tb1;
#pragma unroll
        for (int q = 0; q < 4; q++) {
            ta[q] = make_float4(0.f, 0.f, 0.f, 0.f);
            if (arow_ok) ta[q] = *(const float4*)(arow_p + q * 4);
        }
        tb0 = *(const uint4*)(wrow_p);
        tb1 = *(const uint4*)(wrow_p + 8);
        {
            unsigned int p[8];
#pragma unroll
            for (int q = 0; q < 4; q++) {
                p[2 * q]     = pk2(ta[q].x, ta[q].y);
                p[2 * q + 1] = pk2(ta[q].z, ta[q].w);
            }
            *(uint4*)&As[0][srow][skh] = make_uint4(p[0], p[1], p[2], p[3]);
            *(uint4*)&As[0][srow][skh + 8] = make_uint4(p[4], p[5], p[6], p[7]);
            *(uint4*)&Bs[0][srow][skh] = tb0;
            *(uint4*)&Bs[0][srow][skh + 8] = tb1;
        }
        __syncthreads();
        int cur = 0;
        for (int kt = 0; kt < 512; kt += 32) {
            bool more = (kt + 32 < 512);
            if (more) {   // prefetch next K-tile into regs (flies under MFMA)
#pragma unroll
                for (int q = 0; q < 4; q++) {
                    float4 t4 = make_float4(0.f, 0.f, 0.f, 0.f);
                    if (arow_ok) t4 = *(const float4*)(arow_p + kt + 32 + q * 4);
                    ta[q] = t4;
                }
                tb0 = *(const uint4*)(wrow_p + kt + 32);
                tb1 = *(const uint4*)(wrow_p + kt + 40);
            }
            short8 a[4], b[4];
#pragma unroll
            for (int i = 0; i < 4; i++) a[i] = *(const short8*)&As[cur][wm + i * 16 + l15][quad * 8];
#pragma unroll
            for (int j = 0; j < 4; j++) b[j] = *(const short8*)&Bs[cur][wn + j * 16 + l15][quad * 8];
#pragma unroll
            for (int i = 0; i < 4; i++)
#pragma unroll
                for (int j = 0; j < 4; j++)
                    acc[i][j] = __builtin_amdgcn_mfma_f32_16x16x32_bf16(a[i], b[j], acc[i][j], 0, 0, 0);
            if (more) {   // write next tile into the idle buffer
                unsigned int p[8];
#pragma unroll
                for (int q = 0; q < 4; q++) {
                    p[2 * q]     = pk2(ta[q].x, ta[q].y);
                    p[2 * q + 1] = pk2(ta[q].z, ta[q].w);
                }
                int nxt = cur ^ 1;
                *(uint4*)&As[nxt][srow][skh] = make_uint4(p[0], p[1], p[2], p[3]);
                *(uint4*)&As[nxt][srow][skh + 8] = make_uint4(p[4], p[5], p[6], p[7]);
                *(uint4*)&Bs[nxt][srow][skh] = tb0;
                *(uint4*)&Bs[nxt][srow][skh + 8] = tb1;
            }
            __syncthreads();
            cur ^= 1;
        }
#pragma unroll
        for (int i = 0; i < 4; i++) {
            int mb = m0 + wm + i * 16 + quad * 4;
#pragma unroll
            for (int r = 0; r < 4; r++) {
                int m = mb + r;
                if (m < N_NODES) {
#pragma unroll
                    for (int j = 0; j < 4; j++)
                        hbuf[(size_t)m * 128 + wn + j * 16 + l15] = f2b(acc[i][j][r]);
                }
            }
        }
    } else {
        // ---- edge convert + degree histogram (per-block inline detect) ----
        if (tid == 0) s_any = 0;
        __syncthreads();
        unsigned int probe = words[2 * tid + 1];
        if (probe != 0) atomicAdd(&s_any, 1);
        __syncthreads();
        int f = (s_any == 0) ? 1 : 0;  // 1 => int64 layout
        int e = (blockIdx.x - GEMM1_BLOCKS) * 256 + tid;
        if (e < N_EDGES) {
            unsigned int r = f ? words[2 * (size_t)e] : words[e];
            unsigned int c = f ? words[2 * ((size_t)e + N_EDGES)] : words[e + N_EDGES];
            row[e] = (int)r;
            col[e] = (int)c;
            unsigned int q = __float2uint_rn(ew[e] * 8388608.0f);  // 2^23 fixed point
            unsigned long long old = atomicAdd(&degcnt[c], (1ULL << 32) | (unsigned long long)q);
            slot[e] = (int)(old >> 32);
        }
    }
}

// ---------------------------------------------------------------------------
// dinv + counts + scan phase-1 block reduction; LAST block (ticket) also
// scans the 196 block sums (one-shot arrivals, no polling).
__global__ __launch_bounds__(256) void k_dinv(const unsigned long long* __restrict__ degcnt,
                                              float* __restrict__ dinv,
                                              int* __restrict__ counts,
                                              int* __restrict__ bsum,
                                              int* __restrict__ ticket,
                                              int* __restrict__ bpre,
                                              int* __restrict__ colptr) {
    int i = blockIdx.x * 256 + threadIdx.x;
    int cnt = 0;
    if (i < N_NODES) {
        unsigned long long v = degcnt[i];
        float deg = 1.0f + (float)(unsigned int)(v & 0xffffffffULL) * (1.0f / 8388608.0f);
        dinv[i] = rsqrtf(deg);
        cnt = (int)(v >> 32);
        counts[i] = cnt;
    }
    __shared__ int sh[256];
    __shared__ int s_last;
    sh[threadIdx.x] = cnt;
    __syncthreads();
    for (int ofs = 128; ofs > 0; ofs >>= 1) {
        if (threadIdx.x < ofs) sh[threadIdx.x] += sh[threadIdx.x + ofs];
        __syncthreads();
    }
    if (threadIdx.x == 0) {
        bsum[blockIdx.x] = sh[0];
        __threadfence();
        int t = atomicAdd(ticket, 1);
        s_last = (t == SCAN_BLOCKS - 1) ? 1 : 0;
    }
    __syncthreads();
    if (s_last) {
        __threadfence();
        int t = threadIdx.x;
        int v = (t < SCAN_BLOCKS) ? ((volatile int*)bsum)[t] : 0;
        sh[t] = v;
        __syncthreads();
        for (int ofs = 1; ofs < 256; ofs <<= 1) {
            int u = (t >= ofs) ? sh[t - ofs] : 0;
            __syncthreads();
            sh[t] += u;
            __syncthreads();
        }
        if (t < SCAN_BLOCKS) bpre[t] = sh[t] - v;  // exclusive
        if (t == SCAN_BLOCKS - 1) colptr[N_NODES] = sh[t];
    }
}

__global__ __launch_bounds__(256) void k_scan3(const int* __restrict__ counts,
                                               const int* __restrict__ bpre,
                                               int* __restrict__ colptr) {
    int t = threadIdx.x;
    int i = blockIdx.x * 256 + t;
    int v = (i < N_NODES) ? counts[i] : 0;
    __shared__ int sh[256];
    sh[t] = v;
    __syncthreads();
    for (int ofs = 1; ofs < 256; ofs <<= 1) {
        int u = (t >= ofs) ? sh[t - ofs] : 0;
        __syncthreads();
        sh[t] += u;
        __syncthreads();
    }
    if (i < N_NODES) colptr[i] = bpre[blockIdx.x] + sh[t] - v;
}

// Atomic-free scatter into interleaved (row, norm) records.
__global__ void k_scatter(const int* __restrict__ row, const int* __restrict__ col,
                          const float* __restrict__ ew, const float* __restrict__ dinv,
                          const int* __restrict__ colptr, const int* __restrict__ slot,
                          int2* __restrict__ ern) {
    int e = blockIdx.x * blockDim.x + threadIdx.x;
    if (e < N_EDGES) {
        int c = col[e], r = row[e];
        int p = colptr[c] + slot[e];
        float nrm = dinv[r] * ew[e] * dinv[c];
        ern[p] = make_int2(r, __float_as_int(nrm));
    }
}

// ---------------------------------------------------------------------------
// CSR aggregation FUSED with BN statistics: 1 wave/node (R7-proven optimum),
// 8-edge fully-batched rounds. Grid is EXACT (12500 x 4 waves = 50000 nodes)
// so every wave reaches the stats barrier. Per-block stats reduce in LDS,
// then 256 atomicAdds into one of NREP=64 replicated buffers
// (3.2M atomics / 16K addresses = ~195/address — no hot-line pathology).
// Consumers reduce the replicas in their prologue. Eliminates the 3 bnstats
// launches + gaps. Stats on pre-rounded fp32 (R1-R3 bench-passed semantics).
__global__ __launch_bounds__(256) void k_aggregate(
    const unsigned int* __restrict__ hb, const int* __restrict__ colptr,
    const int2* __restrict__ ern, const float* __restrict__ dinv,
    const float* __restrict__ bias, unsigned int* __restrict__ out, int relu,
    float* __restrict__ sums, float* __restrict__ sumsq) {
    int wave = threadIdx.x >> 6;
    int lane = threadIdx.x & 63;
    int node = blockIdx.x * 4 + wave;   // always < N_NODES (exact grid)
    float di = dinv[node];
    float selfw = di * di;
    unsigned int sv = hb[(size_t)node * 64 + lane];
    float a0 = selfw * blo(sv);
    float a1 = selfw * bhi(sv);
    float c0 = 0.f, c1 = 0.f;
    int start = colptr[node], end = colptr[node + 1];
    for (int e0 = start; e0 < end; e0 += 8) {
        int2 rw[8];
        float wq[8];
#pragma unroll
        for (int q = 0; q < 8; q++) {
            int ee = e0 + q;
            bool ok = ee < end;
            rw[q] = ern[ok ? ee : start];          // clamped, always valid
            wq[q] = ok ? __int_as_float(rw[q].y) : 0.f;
        }
        unsigned int v[8];
#pragma unroll
        for (int q = 0; q < 8; q++) v[q] = hb[(size_t)rw[q].x * 64 + lane];
#pragma unroll
        for (int q = 0; q < 8; q++) {
            if (q & 1) { c0 += wq[q] * blo(v[q]); c1 += wq[q] * bhi(v[q]); }
            else       { a0 += wq[q] * blo(v[q]); a1 += wq[q] * bhi(v[q]); }
        }
    }
    a0 += c0; a1 += c1;
    float2 bv = *(const float2*)&bias[2 * lane];
    a0 += bv.x;
    a1 += bv.y;
    if (relu) { a0 = fmaxf(a0, 0.f); a1 = fmaxf(a1, 0.f); }
    out[(size_t)node * 64 + lane] = pk2(a0, a1);
    // ---- fused BN stats: block reduce -> replicated atomics ----
    __shared__ float red[4][64][4];
    red[wave][lane][0] = a0; red[wave][lane][1] = a0 * a0;
    red[wave][lane][2] = a1; red[wave][lane][3] = a1 * a1;
    __syncthreads();
    if (wave == 0) {
        float s0 = red[0][lane][0] + red[1][lane][0] + red[2][lane][0] + red[3][lane][0];
        float q0 = red[0][lane][1] + red[1][lane][1] + red[2][lane][1] + red[3][lane][1];
        float s1 = red[0][lane][2] + red[1][lane][2] + red[2][lane][2] + red[3][lane][2];
        float q1 = red[0][lane][3] + red[1][lane][3] + red[2][lane][3] + red[3][lane][3];
        int rep = (blockIdx.x & (NREP - 1)) * 128;
        atomicAdd(&sums[rep + 2 * lane], s0);
        atomicAdd(&sums[rep + 2 * lane + 1], s1);
        atomicAdd(&sumsq[rep + 2 * lane], q0);
        atomicAdd(&sumsq[rep + 2 * lane + 1], q1);
    }
}

// ---------------------------------------------------------------------------
// Layer-2/3 GEMM (R7-proven LDS version): A bf16-packed [M,64 uints], BN
// scale/shift computed in the prologue from the NREP replicated stat
// buffers (64 coalesced 512B rows, L2-hot). K=128, reg prefetch.
__global__ __launch_bounds__(256) void k_gemm_h(
    const unsigned int* __restrict__ Ab, const unsigned short* __restrict__ Wt,
    const float* __restrict__ sums, const float* __restrict__ sumsq,
    const float* __restrict__ g, const float* __restrict__ be,
    unsigned short* __restrict__ Out) {
    __shared__ unsigned short As[128][40];
    __shared__ unsigned short Bs[128][40];
    __shared__ float s_sc[128], s_sh[128];
    int tid = threadIdx.x;
    int m0 = blockIdx.x * 128;
    if (tid < 128) {
        float s = 0.f, q = 0.f;
#pragma unroll 8
        for (int r = 0; r < NREP; r++) {
            s += sums[r * 128 + tid];
            q += sumsq[r * 128 + tid];
        }
        const float invn = 1.0f / (float)N_NODES;
        float mu = s * invn;
        float var = q * invn - mu * mu;
        float iv = rsqrtf(var + BN_EPS);
        float sc = g[tid] * iv;
        s_sc[tid] = sc;
        s_sh[tid] = be[tid] - mu * sc;
    }
    __syncthreads();
    int srow = tid >> 1;
    int skh = (tid & 1) << 4;
    int wave = tid >> 6, lane = tid & 63;
    int wm = (wave >> 1) * 64, wn = (wave & 1) * 64;
    int l15 = lane & 15, quad = lane >> 4;
    f32x4 acc[4][4] = {};
    bool arow_ok = (m0 + srow) < N_NODES;
    const unsigned int* arow_b = Ab + (size_t)(m0 + srow) * 64 + (skh >> 1);
    const unsigned short* wrow_p = Wt + (size_t)srow * 128 + skh;
    uint4 r0 = make_uint4(0, 0, 0, 0), r1 = make_uint4(0, 0, 0, 0);
    uint4 tb0, tb1;
    if (arow_ok) {
        r0 = *(const uint4*)(arow_b);
        r1 = *(const uint4*)(arow_b + 4);
    }
    tb0 = *(const uint4*)(wrow_p);
    tb1 = *(const uint4*)(wrow_p + 8);
    for (int kt = 0; kt < 128; kt += 32) {
        unsigned int raw[8] = {r0.x, r0.y, r0.z, r0.w, r1.x, r1.y, r1.z, r1.w};
        unsigned int p[8];
#pragma unroll
        for (int q = 0; q < 8; q++) {
            int ch = kt + skh + 2 * q;
            float f0 = blo(raw[q]) * s_sc[ch] + s_sh[ch];
            float f1 = bhi(raw[q]) * s_sc[ch + 1] + s_sh[ch + 1];
            p[q] = pk2(f0, f1);
        }
        *(uint4*)&As[srow][skh] = make_uint4(p[0], p[1], p[2], p[3]);
        *(uint4*)&As[srow][skh + 8] = make_uint4(p[4], p[5], p[6], p[7]);
        *(uint4*)&Bs[srow][skh] = tb0;
        *(uint4*)&Bs[srow][skh + 8] = tb1;
        __syncthreads();
        if (kt + 32 < 128) {   // prefetch next K-tile under ds_read+MFMA
            if (arow_ok) {
                r0 = *(const uint4*)(arow_b + ((kt + 32) >> 1));
                r1 = *(const uint4*)(arow_b + ((kt + 32) >> 1) + 4);
            }
            tb0 = *(const uint4*)(wrow_p + kt + 32);
            tb1 = *(const uint4*)(wrow_p + kt + 40);
        }
        short8 a[4], b[4];
#pragma unroll
        for (int i = 0; i < 4; i++) a[i] = *(const short8*)&As[wm + i * 16 + l15][quad * 8];
#pragma unroll
        for (int j = 0; j < 4; j++) b[j] = *(const short8*)&Bs[wn + j * 16 + l15][quad * 8];
#pragma unroll
        for (int i = 0; i < 4; i++)
#pragma unroll
            for (int j = 0; j < 4; j++)
                acc[i][j] = __builtin_amdgcn_mfma_f32_16x16x32_bf16(a[i], b[j], acc[i][j], 0, 0, 0);
        __syncthreads();
    }
#pragma unroll
    for (int i = 0; i < 4; i++) {
        int mb = m0 + wm + i * 16 + quad * 4;
#pragma unroll
        for (int r = 0; r < 4; r++) {
            int m = mb + r;
            if (m < N_NODES) {
#pragma unroll
                for (int j = 0; j < 4; j++)
                    Out[(size_t)m * 128 + wn + j * 16 + l15] = f2b(acc[i][j][r]);
            }
        }
    }
}

// ---------------------------------------------------------------------------
// Head: BN3 scale/shift from replicated stats (prologue reduce), x3 fp32
// write, logits+softmax.
__global__ __launch_bounds__(256) void k_logits(const unsigned int* __restrict__ abuf,
                                                const float* __restrict__ sums,
                                                const float* __restrict__ sumsq,
                                                const float* __restrict__ g,
                                                const float* __restrict__ be,
                                                const float* __restrict__ linW,
                                                const float* __restrict__ linb,
                                                float* __restrict__ logits,
                                                float* __restrict__ probs,
                                                float* __restrict__ x3out) {
    __shared__ float Xs[64][130];
    __shared__ float Ws[128 * 40];
    __shared__ float s_sc[128], s_sh[128];
    int tid = threadIdx.x;
    int m0 = blockIdx.x * 64;
    if (tid < 128) {
        float s = 0.f, q = 0.f;
#pragma unroll 8
        for (int r = 0; r < NREP; r++) {
            s += sums[r * 128 + tid];
            q += sumsq[r * 128 + tid];
        }
        const float invn = 1.0f / (float)N_NODES;
        float mu = s * invn;
        float var = q * invn - mu * mu;
        float iv = rsqrtf(var + BN_EPS);
        float sc = g[tid] * iv;
        s_sc[tid] = sc;
        s_sh[tid] = be[tid] - mu * sc;
    }
    for (int q = tid; q < 1280; q += 256)
        *(float4*)&Ws[q * 4] = *(const float4*)&linW[q * 4];
    __syncthreads();
    for (int q = tid; q < 4096; q += 256) {
        int r = q >> 6, u = q & 63;
        int m = m0 + r;
        float f0 = 0.f, f1 = 0.f;
        if (m < N_NODES) {
            unsigned int v = abuf[(size_t)m * 64 + u];
            f0 = blo(v) * s_sc[2 * u] + s_sh[2 * u];
            f1 = bhi(v) * s_sc[2 * u + 1] + s_sh[2 * u + 1];
            *(float2*)&x3out[(size_t)m * 128 + 2 * u] = make_float2(f0, f1);
        }
        *(float2*)&Xs[r][2 * u] = make_float2(f0, f1);
    }
    __syncthreads();
    int r = tid >> 2;
    int cg = tid & 3;
    int cbase = cg * 10;
    float acc[10] = {};
    for (int k = 0; k < 128; k++) {
        float a = Xs[r][k];
#pragma unroll
        for (int j = 0; j < 10; j++) acc[j] += a * Ws[k * 40 + cbase + j];
    }
#pragma unroll
    for (int j = 0; j < 10; j++) acc[j] += linb[cbase + j];
    float m = acc[0];
#pragma unroll
    for (int j = 1; j < 10; j++) m = fmaxf(m, acc[j]);
    m = fmaxf(m, __shfl_xor(m, 1));
    m = fmaxf(m, __shfl_xor(m, 2));
    float ex[10];
    float s = 0.f;
#pragma unroll
    for (int j = 0; j < 10; j++) { ex[j] = expf(acc[j] - m); s += ex[j]; }
    s += __shfl_xor(s, 1);
    s += __shfl_xor(s, 2);
    float inv = 1.0f / s;
    int mrow = m0 + r;
    if (mrow < N_NODES) {
#pragma unroll
        for (int j = 0; j < 10; j += 2) {
            *(float2*)&logits[(size_t)mrow * 40 + cbase + j] = make_float2(acc[j], acc[j + 1]);
            *(float2*)&probs[(size_t)mrow * 40 + cbase + j] = make_float2(ex[j] * inv, ex[j + 1] * inv);
        }
    }
}

// ---------------------------------------------------------------------------
extern "C" void kernel_launch(void* const* d_in, const int* in_sizes, int n_in,
                              void* d_out, int out_size, void* d_ws, size_t ws_size,
                              hipStream_t stream) {
    const float* x = (const float*)d_in[0];
    const unsigned int* eidx = (const unsigned int*)d_in[1];
    const float* ew = (const float*)d_in[2];
    const float* W1 = (const float*)d_in[3];
    const float* b1 = (const float*)d_in[4];
    const float* W2 = (const float*)d_in[5];
    const float* b2 = (const float*)d_in[6];
    const float* W3 = (const float*)d_in[7];
    const float* b3 = (const float*)d_in[8];
    const float* g1 = (const float*)d_in[9];
    const float* be1 = (const float*)d_in[10];
    const float* g2 = (const float*)d_in[11];
    const float* be2 = (const float*)d_in[12];
    const float* g3 = (const float*)d_in[13];
    const float* be3 = (const float*)d_in[14];
    const float* linW = (const float*)d_in[15];
    const float* linb = (const float*)d_in[16];

    float* out = (float*)d_out;
    float* logits = out;
    float* probs = out + (size_t)N_NODES * NCLASS;
    float* x3out = out + 2 * (size_t)N_NODES * NCLASS;

    char* ws = (char*)d_ws;
    size_t off = 0;
    auto take = [&](size_t bytes) -> char* {
        char* p = ws + off;
        off += (bytes + 255) & ~(size_t)255;
        return p;
    };
    int* row32 = (int*)take((size_t)N_EDGES * 4);
    int* col32 = (int*)take((size_t)N_EDGES * 4);
    int* slot = (int*)take((size_t)N_EDGES * 4);
    int* colptr = (int*)take((size_t)(N_NODES + 1) * 4);
    int* counts = (int*)take((size_t)N_NODES * 4);
    unsigned long long* degcnt = (unsigned long long*)take((size_t)N_NODES * 8);
    int2* ern = (int2*)take((size_t)N_EDGES * 8);
    float* dinv = (float*)take((size_t)N_NODES * 4);
    unsigned short* hbuf = (unsigned short*)take((size_t)N_NODES * NHID * 2);
    unsigned short* abuf = (unsigned short*)take((size_t)N_NODES * NHID * 2);
    unsigned short* W1t = (unsigned short*)take((size_t)512 * 128 * 2);
    unsigned short* W2t = (unsigned short*)take((size_t)128 * 128 * 2);
    unsigned short* W3t = (unsigned short*)take((size_t)128 * 128 * 2);
    float* stats = (float*)take((size_t)49152 * 4);  // 3 layers x {sums,sumsq} x [64][128]
    int* syncp = (int*)take(8 * 4);                  // [0]=dinv ticket
    int* bsum = (int*)take((size_t)SCAN_BLOCKS * 4);
    int* bpre = (int*)take((size_t)SCAN_BLOCKS * 4);
    (void)ws_size; (void)n_in; (void)in_sizes; (void)out_size;

    float* sums1 = stats,          *sumsq1 = stats + 8192;
    float* sums2 = stats + 16384,  *sumsq2 = stats + 24576;
    float* sums3 = stats + 32768,  *sumsq3 = stats + 40960;

    const int TPB = 256;

    // preprocessing + layer-1 GEMM overlapped with edge histogram (fat)
    k_prep_w<<<(98304 + TPB - 1) / TPB, TPB, 0, stream>>>(W1, W2, W3, W1t, W2t, W3t, degcnt, stats, syncp);
    k_fat<<<GEMM1_BLOCKS + EDGE_BLOCKS, TPB, 0, stream>>>(
        x, W1t, hbuf, eidx, ew, row32, col32, degcnt, slot);
    k_dinv<<<SCAN_BLOCKS, TPB, 0, stream>>>(degcnt, dinv, counts, bsum, &syncp[0], bpre, colptr);
    k_scan3<<<SCAN_BLOCKS, TPB, 0, stream>>>(counts, bpre, colptr);
    k_scatter<<<EDGE_BLOCKS, TPB, 0, stream>>>(row32, col32, ew, dinv, colptr, slot, ern);

    // layer 1 (aggregate + BN1 stats fused)
    k_aggregate<<<AGG_BLOCKS, TPB, 0, stream>>>((const unsigned int*)hbuf, colptr, ern, dinv, b1, (unsigned int*)abuf, 1, sums1, sumsq1);

    // layer 2 (BN1 applied inline in GEMM prologue from replicated sums)
    k_gemm_h<<<GEMMH_BLOCKS, TPB, 0, stream>>>((const unsigned int*)abuf, W2t, sums1, sumsq1, g1, be1, hbuf);
    k_aggregate<<<AGG_BLOCKS, TPB, 0, stream>>>((const unsigned int*)hbuf, colptr, ern, dinv, b2, (unsigned int*)abuf, 1, sums2, sumsq2);

    // layer 3
    k_gemm_h<<<GEMMH_BLOCKS, TPB, 0, stream>>>((const unsigned int*)abuf, W3t, sums2, sumsq2, g2, be2, hbuf);
    k_aggregate<<<AGG_BLOCKS, TPB, 0, stream>>>((const unsigned int*)hbuf, colptr, ern, dinv, b3, (unsigned int*)abuf, 0, sums3, sumsq3);

    // head: BN3 apply (inline) + x3 write + logits + softmax
    k_logits<<<(N_NODES + 63) / 64, TPB, 0, stream>>>((const unsigned int*)abuf, sums3, sumsq3, g3, be3, linW, linb, logits, probs, x3out);
}